// Round 5
// baseline (89997.986 us; speedup 1.0000x reference)
//
#include <hip/hip_runtime.h>
#include <math.h>

#define NS 32768

static __device__ __forceinline__ float leakyf(float x){ return x >= 0.f ? x : 0.2f*x; }

// ---------------- weight transpose for dilated stack: wT[l][sg][j][cc][o] ----------------
__global__ void k_wtrans(const float* __restrict__ ws, const float* __restrict__ wg, float* __restrict__ wT)
{
    int idx = blockIdx.x*256 + threadIdx.x;
    const int total = 7*2*3*128*128;
    if (idx >= total) return;
    int o  = idx & 127;
    int cc = (idx >> 7) & 127;
    int j  = (idx >> 14) % 3;
    int sg = (idx / 49152) & 1;
    int l  = idx / 98304;
    const float* src = sg ? wg : ws;
    wT[idx] = src[((l*128 + o)*128 + cc)*3 + j];
}

// ---------------- stage-2 weight transpose: woT/wnT [l][c][o] ----------------
__global__ void k_wtrans2(const float* __restrict__ wo, const float* __restrict__ wn,
                          float* __restrict__ woT, float* __restrict__ wnT)
{
    int idx = blockIdx.x*256 + threadIdx.x;
    if (idx >= 7*128*128) return;
    int o = idx & 127;
    int c = (idx >> 7) & 127;
    int l = idx >> 14;
    woT[idx] = wo[(l*128 + o)*128 + c];
    wnT[idx] = wn[(l*128 + o)*128 + c];
}

// ---------------- conv_up weight transposes ----------------
// wtu[(mode*4+layer)][c][j][o=128]   (8*128*3*128 = 393216)
// wtf[c][j][ctp=520 (zero-padded)]   (128*3*520   = 199680)
__global__ void k_wtrans_up(const float* __restrict__ ecw, const float* __restrict__ tcw,
                            const float* __restrict__ tfw, float* __restrict__ wtu, float* __restrict__ wtf)
{
    int idx = blockIdx.x*256 + threadIdx.x;
    if (idx < 393216) {
        int o = idx & 127;
        int j = (idx >> 7) % 3;
        int c = (idx / 384) & 127;
        int ml = idx / 49152;
        const float* src = (ml < 4 ? ecw : tcw) + (ml & 3)*49152;
        wtu[idx] = src[(o*128 + c)*3 + j];
    }
    if (idx < 199680) {
        int ct = idx % 520;
        int j = (idx / 520) % 3;
        int c = idx / 1560;
        wtf[idx] = (ct < 514) ? tfw[(ct*128 + c)*3 + j] : 0.f;
    }
}

// ---------------- front conv: n[b,c,t] = sum_k x[b, t+k-256] * fbw[c,k] ----------------
__global__ __launch_bounds__(512) void k_front(const float* __restrict__ x, const float* __restrict__ fbw,
                                               float* __restrict__ n0)
{
    int b = blockIdx.y;
    int t0 = blockIdx.x * 64;
    int tid = threadIdx.x;
    int t = tid & 63, og = tid >> 6;
    __shared__ float xs[576];
    __shared__ float4 wl[2048]; // [c][k4] 64 k per chunk
    for (int i = tid; i < 575; i += 512) {
        int p = t0 + i - 256;
        xs[i] = ((unsigned)p < NS) ? x[b*NS + p] : 0.f;
    }
    float s[16];
    #pragma unroll
    for (int i = 0; i < 16; ++i) s[i] = 0.f;
    for (int kc = 0; kc < 8; ++kc) {
        __syncthreads();
        for (int i = tid; i < 2048; i += 512) {
            int c = i >> 4, k4 = i & 15;
            wl[i] = *(const float4*)(fbw + c*512 + kc*64 + k4*4);
        }
        __syncthreads();
        for (int k4 = 0; k4 < 16; ++k4) {
            int base = t + kc*64 + k4*4;
            float xv0 = xs[base+0], xv1 = xs[base+1], xv2 = xs[base+2], xv3 = xs[base+3];
            #pragma unroll
            for (int i = 0; i < 16; ++i) {
                float4 w = wl[(og*16 + i)*16 + k4];
                s[i] += w.x*xv0 + w.y*xv1 + w.z*xv2 + w.w*xv3;
            }
        }
    }
    #pragma unroll
    for (int i = 0; i < 16; ++i)
        n0[(size_t)(b*128 + og*16 + i)*NS + t0 + t] = s[i];
}

// ---------------- one dilated gated layer ----------------
// j-sequential, cc-chunked, 2 time-points/thread, 80KB LDS -> 2 blocks/CU.
// pool (floats, 20480 = 80KB):
//   stage1: strip[2] @0,@2048 (16cc x 128t each) | wbuf[2] @4096,@8192 ([2sg][16cc][128o] each)
//   stage2: h @0..16384 ([128cc][128t])          | w2buf[2] @16384,@18432 ([2arm][8cc][128o] each)
__global__ __launch_bounds__(512, 2) void k_layer(const float* __restrict__ nin, float* __restrict__ nout,
        float* __restrict__ acc, const float* __restrict__ wTl,
        const float* __restrict__ bs, const float* __restrict__ bg,
        const float* __restrict__ woTl, const float* __restrict__ bo,
        const float* __restrict__ wnTl, const float* __restrict__ bn,
        int d, int first)
{
    __shared__ float pool[20480];
    int b = blockIdx.y;
    int t0 = blockIdx.x * 128;
    int tid = threadIdx.x;
    int l = tid & 63, wg = tid >> 6;       // 8 o-groups of 16
    int o0 = wg * 16;
    const float* nb = nin + (size_t)b*128*NS;
    const float4* wg4p = (const float4*)wTl;

    // prefetch helpers (inline)
    int sci = tid >> 5;                    // strip: cc-in-chunk
    int st4 = (tid & 31) * 4;              // strip: t offset (x4)
    int wci = (tid >> 5) & 15, wo4 = tid & 31;  // weights

    float4 sreg, wreg0, wreg1;
    {   // chunk (j=0, cb=0)
        int p = t0 + st4 + (0-1)*d;
        const float* basep = nb + (size_t)(0*16 + sci)*NS;
        float v0 = ((unsigned)(p+0) < NS) ? basep[p+0] : 0.f;
        float v1 = ((unsigned)(p+1) < NS) ? basep[p+1] : 0.f;
        float v2 = ((unsigned)(p+2) < NS) ? basep[p+2] : 0.f;
        float v3 = ((unsigned)(p+3) < NS) ? basep[p+3] : 0.f;
        sreg = make_float4(v0,v1,v2,v3);
        wreg0 = wg4p[((0*3 + 0)*128 + wci)*32 + wo4];
        wreg1 = wg4p[((1*3 + 0)*128 + wci)*32 + wo4];
    }

    float s0[16], s1[16], g0[16], g1[16];
    #pragma unroll
    for (int i = 0; i < 16; ++i) { float bsv = bs[o0+i], bgv = bg[o0+i]; s0[i]=bsv; s1[i]=bsv; g0[i]=bgv; g1[i]=bgv; }

    int cnt = 0;
    for (int j = 0; j < 3; ++j) {
        for (int cb = 0; cb < 8; ++cb, ++cnt) {
            int cur = cnt & 1;
            *(float4*)(pool + cur*2048 + tid*4) = sreg;
            {
                float4* wb = (float4*)(pool + 4096 + cur*4096);
                wb[tid] = wreg0; wb[tid + 512] = wreg1;
            }
            if (cnt < 23) {
                int jn = (cb == 7) ? j+1 : j;
                int cbn = (cb == 7) ? 0 : cb+1;
                int p = t0 + st4 + (jn-1)*d;
                const float* basep = nb + (size_t)(cbn*16 + sci)*NS;
                float v0 = ((unsigned)(p+0) < NS) ? basep[p+0] : 0.f;
                float v1 = ((unsigned)(p+1) < NS) ? basep[p+1] : 0.f;
                float v2 = ((unsigned)(p+2) < NS) ? basep[p+2] : 0.f;
                float v3 = ((unsigned)(p+3) < NS) ? basep[p+3] : 0.f;
                sreg = make_float4(v0,v1,v2,v3);
                wreg0 = wg4p[((0*3 + jn)*128 + cbn*16 + wci)*32 + wo4];
                wreg1 = wg4p[((1*3 + jn)*128 + cbn*16 + wci)*32 + wo4];
            }
            __syncthreads();
            const float* sb = pool + cur*2048;
            const float4* wbS = (const float4*)(pool + 4096 + cur*4096);
            const float4* wbG = wbS + 512;
            for (int ccx = 0; ccx < 16; ++ccx) {
                float nv0 = sb[ccx*128 + l];
                float nv1 = sb[ccx*128 + 64 + l];
                const float4* ws4 = wbS + ccx*32 + wg*4;
                const float4* wgv = wbG + ccx*32 + wg*4;
                #pragma unroll
                for (int i4 = 0; i4 < 4; ++i4) {
                    float4 a4 = ws4[i4], b4 = wgv[i4];
                    s0[i4*4+0] += nv0*a4.x; s0[i4*4+1] += nv0*a4.y; s0[i4*4+2] += nv0*a4.z; s0[i4*4+3] += nv0*a4.w;
                    s1[i4*4+0] += nv1*a4.x; s1[i4*4+1] += nv1*a4.y; s1[i4*4+2] += nv1*a4.z; s1[i4*4+3] += nv1*a4.w;
                    g0[i4*4+0] += nv0*b4.x; g0[i4*4+1] += nv0*b4.y; g0[i4*4+2] += nv0*b4.z; g0[i4*4+3] += nv0*b4.w;
                    g1[i4*4+0] += nv1*b4.x; g1[i4*4+1] += nv1*b4.y; g1[i4*4+2] += nv1*b4.z; g1[i4*4+3] += nv1*b4.w;
                }
            }
        }
    }

    // gated activation -> h in LDS
    float hv0[16], hv1[16];
    #pragma unroll
    for (int i = 0; i < 16; ++i) {
        hv0[i] = tanhf(s0[i]) * (1.f/(1.f + __expf(-g0[i])));
        hv1[i] = tanhf(s1[i]) * (1.f/(1.f + __expf(-g1[i])));
    }
    __syncthreads();   // all stage-1 LDS reads done before overwrite
    #pragma unroll
    for (int i = 0; i < 16; ++i) {
        pool[(o0+i)*128 + l]      = hv0[i];
        pool[(o0+i)*128 + 64 + l] = hv1[i];
    }

    // stage-2 weight prefetch chunk 0
    int aarm = tid >> 8, arem = tid & 255;
    int aci = arem >> 5, ao4 = arem & 31;
    float4 w2r;
    {
        const float4* srcw = (const float4*)(aarm ? wnTl : woTl);
        w2r = srcw[(0*8 + aci)*32 + ao4];
    }

    float a0[16], a1[16], n0r[16], n1r[16];
    #pragma unroll
    for (int i = 0; i < 16; ++i) { a0[i]=0.f; a1[i]=0.f; n0r[i]=0.f; n1r[i]=0.f; }

    for (int cb2 = 0; cb2 < 16; ++cb2) {
        int cur = cb2 & 1;
        ((float4*)(pool + 16384 + cur*2048))[tid] = w2r;
        if (cb2 < 15) {
            const float4* srcw = (const float4*)(aarm ? wnTl : woTl);
            w2r = srcw[((cb2+1)*8 + aci)*32 + ao4];
        }
        __syncthreads();
        const float4* w2S = (const float4*)(pool + 16384 + cur*2048);
        const float4* w2N = w2S + 256;
        for (int ccx = 0; ccx < 8; ++ccx) {
            float h0 = pool[(cb2*8 + ccx)*128 + l];
            float h1 = pool[(cb2*8 + ccx)*128 + 64 + l];
            const float4* wo4p = w2S + ccx*32 + wg*4;
            const float4* wn4p = w2N + ccx*32 + wg*4;
            #pragma unroll
            for (int i4 = 0; i4 < 4; ++i4) {
                float4 w0 = wo4p[i4], w1 = wn4p[i4];
                a0[i4*4+0] += h0*w0.x; a0[i4*4+1] += h0*w0.y; a0[i4*4+2] += h0*w0.z; a0[i4*4+3] += h0*w0.w;
                a1[i4*4+0] += h1*w0.x; a1[i4*4+1] += h1*w0.y; a1[i4*4+2] += h1*w0.z; a1[i4*4+3] += h1*w0.w;
                n0r[i4*4+0] += h0*w1.x; n0r[i4*4+1] += h0*w1.y; n0r[i4*4+2] += h0*w1.z; n0r[i4*4+3] += h0*w1.w;
                n1r[i4*4+0] += h1*w1.x; n1r[i4*4+1] += h1*w1.y; n1r[i4*4+2] += h1*w1.z; n1r[i4*4+3] += h1*w1.w;
            }
        }
    }

    #pragma unroll
    for (int i = 0; i < 16; ++i) {
        int o = o0 + i;
        float bov = bo[o], bnv = bn[o];
        size_t gi0 = (size_t)(b*128 + o)*NS + t0 + l;
        size_t gi1 = gi0 + 64;
        float av0 = first ? 0.f : acc[gi0];
        float av1 = first ? 0.f : acc[gi1];
        acc[gi0] = av0 + a0[i] + bov;
        acc[gi1] = av1 + a1[i] + bov;
        nout[gi0] = n0r[i] + bnv + nin[gi0];
        nout[gi1] = n1r[i] + bnv + nin[gi1];
    }
}

// ---------------- norms^2 over channels ----------------
__global__ void k_norms(const float* __restrict__ xf, float* __restrict__ norms)
{
    int b = blockIdx.y;
    int t = blockIdx.x*256 + threadIdx.x;
    float a = 0.f;
    for (int c = 0; c < 128; ++c) {
        float v = xf[(size_t)(b*128 + c)*NS + t];
        a += v*v;
    }
    norms[b*NS + t] = a;
}

// ---------------- top-32 per batch (destroys norms) ----------------
__global__ __launch_bounds__(1024) void k_topk(float* __restrict__ norms, float* __restrict__ topv, int* __restrict__ topi)
{
    int b = blockIdx.x;
    int tid = threadIdx.x;
    __shared__ float rv[1024];
    __shared__ int   ri[1024];
    for (int it = 0; it < 32; ++it) {
        float best = -2.f; int bi = 0;
        for (int k = tid; k < NS; k += 1024) {
            float v = norms[b*NS + k];
            if (v > best) { best = v; bi = k; }
        }
        rv[tid] = best; ri[tid] = bi;
        __syncthreads();
        for (int off = 512; off > 0; off >>= 1) {
            if (tid < off) {
                float ov = rv[tid+off]; int oi = ri[tid+off];
                if (ov > rv[tid] || (ov == rv[tid] && oi < ri[tid])) { rv[tid] = ov; ri[tid] = oi; }
            }
            __syncthreads();
        }
        if (tid == 0) {
            topv[b*32 + it] = sqrtf(rv[0]);
            topi[b*32 + it] = ri[0];
            norms[b*NS + ri[0]] = -1.f;
        }
        __syncthreads();
    }
}

// ---------------- gather latents ----------------
__global__ void k_latents(const float* __restrict__ xf, const int* __restrict__ topi, float* __restrict__ lat)
{
    int ev = blockIdx.x; int c = threadIdx.x;
    int b = ev >> 5;
    int idx = topi[ev];
    lat[ev*128 + c] = xf[(size_t)(b*128 + c)*NS + idx];
}

// ---------------- agg = max over time ----------------
__global__ void k_aggmax(const float* __restrict__ xf, float* __restrict__ agg)
{
    int rc = blockIdx.x;
    int tid = threadIdx.x;
    __shared__ float red[256];
    float m = -3.4e38f;
    const float* row = xf + (size_t)rc*NS;
    for (int t = tid; t < NS; t += 256) m = fmaxf(m, row[t]);
    red[tid] = m; __syncthreads();
    for (int off = 128; off > 0; off >>= 1) {
        if (tid < off) red[tid] = fmaxf(red[tid], red[tid+off]);
        __syncthreads();
    }
    if (tid == 0) agg[rc] = red[0];
}

// ---------------- generic upsample layer: repeat(2) + conv3(pad1) + leaky ----------------
template<int L2>
__device__ __forceinline__ void up_layer(const float* __restrict__ wbase, const float* __restrict__ bias,
                                         const float* __restrict__ inb, float* __restrict__ outb,
                                         float* __restrict__ wst, int tid)
{
    constexpr int NO  = L2/4;
    constexpr int Lin = L2/2;
    constexpr int LOG = (L2==16)?4:(L2==32)?5:6;
    int p  = tid & (L2-1);
    int og = tid >> LOG;
    int o0 = og*NO;
    float acc[NO];
    #pragma unroll
    for (int k = 0; k < NO; ++k) acc[k] = 0.f;
    for (int cc0 = 0; cc0 < 128; cc0 += 16) {
        __syncthreads();
        for (int k = tid; k < 6144; k += 512) wst[k] = wbase[cc0*384 + k];
        __syncthreads();
        for (int ci = 0; ci < 16; ++ci) {
            int c = cc0 + ci;
            float xv[3];
            #pragma unroll
            for (int j = 0; j < 3; ++j) {
                int iu = p + j - 1;
                xv[j] = ((unsigned)iu < (unsigned)L2) ? inb[c*Lin + (iu>>1)] : 0.f;
            }
            #pragma unroll
            for (int j = 0; j < 3; ++j) {
                const float4* w4 = (const float4*)(wst + (ci*3 + j)*128 + o0);
                #pragma unroll
                for (int q = 0; q < NO/4; ++q) {
                    float4 w = w4[q];
                    acc[q*4+0] += xv[j]*w.x; acc[q*4+1] += xv[j]*w.y;
                    acc[q*4+2] += xv[j]*w.z; acc[q*4+3] += xv[j]*w.w;
                }
            }
        }
    }
    #pragma unroll
    for (int k = 0; k < NO; ++k) outb[(o0+k)*L2 + p] = leakyf(acc[k] + bias[o0+k]);
}

// L2=128 layer in two o-halves (NO=16/thread, no spills); stages only the needed 64-o slice
__device__ __forceinline__ void up_layer128(const float* __restrict__ wbase, const float* __restrict__ bias,
                                            const float* __restrict__ inb, float* __restrict__ outb,
                                            float* __restrict__ wst, int tid, int half)
{
    int p  = tid & 127;
    int og = tid >> 7;      // 0..3
    int o0 = og*16;         // local offset within the 64-o half
    float acc[16];
    #pragma unroll
    for (int k = 0; k < 16; ++k) acc[k] = 0.f;
    for (int cc0 = 0; cc0 < 128; cc0 += 16) {
        __syncthreads();
        for (int k = tid; k < 3072; k += 512) {
            int ci = k / 192, rem = k - ci*192;
            int j = rem >> 6, o = rem & 63;
            wst[k] = wbase[(cc0+ci)*384 + j*128 + half*64 + o];
        }
        __syncthreads();
        for (int ci = 0; ci < 16; ++ci) {
            int c = cc0 + ci;
            float xv[3];
            #pragma unroll
            for (int j = 0; j < 3; ++j) {
                int iu = p + j - 1;
                xv[j] = ((unsigned)iu < 128u) ? inb[c*64 + (iu>>1)] : 0.f;
            }
            #pragma unroll
            for (int j = 0; j < 3; ++j) {
                const float4* w4 = (const float4*)(wst + ci*192 + j*64 + o0);
                #pragma unroll
                for (int q = 0; q < 4; ++q) {
                    float4 w = w4[q];
                    acc[q*4+0] += xv[j]*w.x; acc[q*4+1] += xv[j]*w.y;
                    acc[q*4+2] += xv[j]*w.z; acc[q*4+3] += xv[j]*w.w;
                }
            }
        }
    }
    #pragma unroll
    for (int k = 0; k < 16; ++k) {
        int o = half*64 + o0 + k;
        outb[o*128 + p] = leakyf(acc[k] + bias[o]);
    }
}

// ---------------- fused conv_up: gridDim=(128 events, 2 modes), 512 threads ----------------
__global__ __launch_bounds__(512) void k_convup2(const float* __restrict__ lat,
    const float* __restrict__ elw, const float* __restrict__ elb, const float* __restrict__ ecb,
    const float* __restrict__ efw, const float* __restrict__ efb,
    const float* __restrict__ tlw, const float* __restrict__ tlb, const float* __restrict__ tcb,
    const float* __restrict__ tfb, const float* __restrict__ wtu, const float* __restrict__ wtf,
    float* __restrict__ envsq, float* __restrict__ tfT)
{
    __shared__ float pool[39104]; // 152.75 KB
    float* latv = pool;           // 128
    float* bufA = pool + 128;     // 8256 (doubles as trb, stride 129)
    float* bufB = pool + 8384;    // 8192
    float* bufC = pool + 16576;   // 16384
    float* wst  = pool + 32960;   // 6144
    int ev = blockIdx.x;
    int m  = blockIdx.y;
    int tid = threadIdx.x;
    const float* lw = m ? tlw : elw;
    const float* lb = m ? tlb : elb;
    const float* cb = m ? tcb : ecb;
    const float* wu = wtu + m*4*49152;
    if (tid < 128) latv[tid] = lat[ev*128 + tid];
    __syncthreads();
    for (int jj = tid; jj < 1024; jj += 512) {
        float a = lb[jj];
        const float4* w4 = (const float4*)(lw + jj*128);
        #pragma unroll 8
        for (int q = 0; q < 32; ++q) {
            float4 w = w4[q];
            a += w.x*latv[q*4] + w.y*latv[q*4+1] + w.z*latv[q*4+2] + w.w*latv[q*4+3];
        }
        bufA[(jj>>3)*8 + (jj&7)] = a;
    }
    up_layer<16>(wu,        cb,     bufA, bufB, wst, tid);
    up_layer<32>(wu+49152,  cb+128, bufB, bufA, wst, tid);
    up_layer<64>(wu+98304,  cb+256, bufA, bufB, wst, tid);
    up_layer128(wu+147456, cb+384, bufB, bufC, wst, tid, 0);
    up_layer128(wu+147456, cb+384, bufB, bufC, wst, tid, 1);
    __syncthreads();
    int p = tid & 127, g = tid >> 7;
    if (m == 0) {
        float s = 0.f;
        for (int c = g*32; c < g*32+32; ++c) {
            #pragma unroll
            for (int j = 0; j < 3; ++j) {
                int iu = p + j - 1;
                float xv = ((unsigned)iu < 128u) ? bufC[c*128 + iu] : 0.f;
                s += efw[c*3+j]*xv;
            }
        }
        wst[g*128 + p] = s;
        __syncthreads();
        if (g == 0) {
            float a = wst[p] + wst[128+p] + wst[256+p] + wst[384+p] + efb[0];
            envsq[ev*128 + p] = a*a;
        }
    } else {
        float* trb = bufA;   // [64ct][stride 129] transpose buffer
        for (int ctb = 0; ctb < 9; ++ctb) {
            int ct0 = ctb*64;
            float acc[16];
            #pragma unroll
            for (int i = 0; i < 16; ++i) acc[i] = 0.f;
            for (int cc0 = 0; cc0 < 128; cc0 += 16) {
                __syncthreads();
                for (int k = tid; k < 3072; k += 512) {
                    int ci = k / 192, rem = k - ci*192;
                    int j = rem >> 6, ct = rem & 63;
                    wst[k] = wtf[(cc0+ci)*1560 + j*520 + ct0 + ct];
                }
                __syncthreads();
                for (int ci = 0; ci < 16; ++ci) {
                    int c = cc0 + ci;
                    float xv[3];
                    #pragma unroll
                    for (int j = 0; j < 3; ++j) {
                        int iu = p + j - 1;
                        xv[j] = ((unsigned)iu < 128u) ? bufC[c*128 + iu] : 0.f;
                    }
                    #pragma unroll
                    for (int j = 0; j < 3; ++j) {
                        const float4* w4 = (const float4*)(wst + ci*192 + j*64 + g*16);
                        #pragma unroll
                        for (int q = 0; q < 4; ++q) {
                            float4 w = w4[q];
                            acc[q*4+0] += xv[j]*w.x; acc[q*4+1] += xv[j]*w.y;
                            acc[q*4+2] += xv[j]*w.z; acc[q*4+3] += xv[j]*w.w;
                        }
                    }
                }
            }
            __syncthreads();      // previous trb consumers done
            #pragma unroll
            for (int i = 0; i < 16; ++i) trb[(g*16 + i)*129 + p] = acc[i];
            __syncthreads();
            int ctl = tid & 63, pg = tid >> 6;
            #pragma unroll
            for (int pass = 0; pass < 16; ++pass) {
                int pp = pass*8 + pg;
                int ct = ct0 + ctl;
                if (ct < 514)
                    tfT[(size_t)(ev*128 + pp)*514 + ct] = trb[ctl*129 + pp] + tfb[ct];
            }
        }
    }
}

// ---------------- impulse transfer lin_stack ----------------
__global__ __launch_bounds__(128) void k_itf(const float* __restrict__ lat,
    const float* __restrict__ iw, const float* __restrict__ ib,
    const float* __restrict__ iow, const float* __restrict__ iob,
    float* __restrict__ itf)
{
    int ev = blockIdx.x; int tid = threadIdx.x;
    __shared__ float xa[128], xb[128];
    xa[tid] = lat[ev*128 + tid];
    __syncthreads();
    float* src = xa; float* dst = xb;
    for (int l = 0; l < 3; ++l) {
        float a = ib[l*128 + tid];
        const float* wr = iw + (l*128 + tid)*128;
        for (int k = 0; k < 128; ++k) a += wr[k]*src[k];
        dst[tid] = leakyf(a);
        __syncthreads();
        float* tmp = src; src = dst; dst = tmp;
    }
    for (int o = tid; o < 514; o += 128) {
        float a = iob[o];
        const float* wr = iow + o*128;
        for (int k = 0; k < 128; ++k) a += wr[k]*src[k];
        itf[ev*514 + o] = a;
    }
}

// ---------------- room/mix lin_stacks + softmax ----------------
__global__ __launch_bounds__(128) void k_roommix(const float* __restrict__ agg,
    const float* __restrict__ rw, const float* __restrict__ rb,
    const float* __restrict__ row_, const float* __restrict__ rob,
    const float* __restrict__ mw, const float* __restrict__ mb,
    const float* __restrict__ mow, const float* __restrict__ mob,
    float* __restrict__ probs, float* __restrict__ mval)
{
    int b = blockIdx.x; int tid = threadIdx.x;
    __shared__ float xa[128], xb[128], rr[8];
    xa[tid] = agg[b*128 + tid];
    __syncthreads();
    float* src = xa; float* dst = xb;
    for (int l = 0; l < 3; ++l) {
        float a = rb[l*128 + tid];
        const float* wr = rw + (l*128 + tid)*128;
        for (int k = 0; k < 128; ++k) a += wr[k]*src[k];
        dst[tid] = leakyf(a);
        __syncthreads();
        float* tmp = src; src = dst; dst = tmp;
    }
    if (tid < 8) {
        float a = rob[tid];
        const float* wr = row_ + tid*128;
        for (int k = 0; k < 128; ++k) a += wr[k]*src[k];
        rr[tid] = a;
    }
    __syncthreads();
    if (tid == 0) {
        float m = rr[0];
        for (int j = 1; j < 8; ++j) m = fmaxf(m, rr[j]);
        float ssum = 0.f; float e[8];
        for (int j = 0; j < 8; ++j) { e[j] = __expf(rr[j]-m); ssum += e[j]; }
        for (int j = 0; j < 8; ++j) probs[b*8+j] = e[j]/ssum;
    }
    __syncthreads();
    xa[tid] = agg[b*128 + tid];
    __syncthreads();
    src = xa; dst = xb;
    for (int l = 0; l < 3; ++l) {
        float a = mb[l*128 + tid];
        const float* wr = mw + (l*128 + tid)*128;
        for (int k = 0; k < 128; ++k) a += wr[k]*src[k];
        dst[tid] = leakyf(a);
        __syncthreads();
        float* tmp = src; src = dst; dst = tmp;
    }
    if (tid == 0) {
        float a = mob[0];
        for (int k = 0; k < 128; ++k) a += mow[k]*src[k];
        mval[b] = a;
    }
}

// ---------------- ir = softmax(r) @ rooms ----------------
__global__ void k_ir(const float* __restrict__ probs, const float* __restrict__ rooms, float* __restrict__ ir)
{
    int b = blockIdx.y;
    int t = blockIdx.x*256 + threadIdx.x;
    float a = 0.f;
    for (int j = 0; j < 8; ++j) a += probs[b*8+j]*rooms[j*NS + t];
    ir[b*NS + t] = a;
}

// ---------------- 512-pt complex FFT in LDS (256 threads) ----------------
__device__ __forceinline__ void fft512(float* re, float* im, const float* twr, const float* twi, int tid, bool inverse)
{
    for (int w = tid; w < 512; w += 256) {
        unsigned r = __brev((unsigned)w) >> 23;
        if ((int)r > w) {
            float tr = re[w]; re[w] = re[r]; re[r] = tr;
            float ti = im[w]; im[w] = im[r]; im[r] = ti;
        }
    }
    __syncthreads();
    for (int s = 0; s < 9; ++s) {
        int half = 1 << s;
        int grp = tid >> s;
        int pos = tid & (half-1);
        int i0 = (grp << (s+1)) + pos;
        int i1 = i0 + half;
        int twidx = pos << (8 - s);
        float wr = twr[twidx];
        float wi = inverse ? -twi[twidx] : twi[twidx];
        float r1 = re[i1], q1 = im[i1];
        float tr = wr*r1 - wi*q1;
        float ti = wr*q1 + wi*r1;
        float r0 = re[i0], q0 = im[i0];
        re[i1] = r0 - tr; im[i1] = q0 - ti;
        re[i0] = r0 + tr; im[i0] = q0 + ti;
        __syncthreads();
    }
}

// ---------------- per-event scan: impulse -> 128 frames of env*imp + carry -> FFT filter -> OLA ----------------
__global__ __launch_bounds__(256) void k_event(const float* __restrict__ tfT, const float* __restrict__ itf,
    const float* __restrict__ envsq, const float* __restrict__ noise, float* __restrict__ atoms)
{
    int ev = blockIdx.x; int tid = threadIdx.x;
    __shared__ float twr[256], twi[256];
    __shared__ float re[512], im[512], carry[512], imp[512], ham[512], acc[256], envl[128];
    if (tid < 128) envl[tid] = envsq[ev*128 + tid];
    {
        float ang = -6.283185307179586f * (float)tid / 512.0f;
        float si, co;
        sincosf(ang, &si, &co);
        twr[tid] = co; twi[tid] = si;
    }
    for (int w = tid; w < 512; w += 256) {
        ham[w] = 0.54f - 0.46f*cosf(6.283185307179586f * (float)w / 512.0f);
        re[w] = noise[w]; im[w] = 0.f; carry[w] = 0.f;
    }
    acc[tid] = 0.f;
    __syncthreads();
    fft512(re, im, twr, twi, tid, false);
    {
        const float* tp = itf + ev*514;
        int k = tid;
        float xr = re[k], xi = im[k];
        float tr = tp[2*k], ti = tp[2*k+1];
        float sr = xr*tr - xi*ti;
        float si = xr*ti + xi*tr;
        if (k == 0) si = 0.f;
        re[k] = sr; im[k] = si;
        if (k >= 1) { re[512-k] = sr; im[512-k] = -si; }
        if (tid == 0) {
            float xr2 = re[256], xi2 = im[256];
            float sr2 = xr2*tp[512] - xi2*tp[513];
            re[256] = sr2; im[256] = 0.f;
        }
    }
    __syncthreads();
    fft512(re, im, twr, twi, tid, true);
    for (int w = tid; w < 512; w += 256) imp[w] = re[w] * (1.0f/512.0f);
    __syncthreads();
    const float inv512 = 1.0f/512.0f;
    for (int f = 0; f < 128; ++f) {
        for (int w = tid; w < 512; w += 256) {
            int tg = f*256 + w;
            float e = 0.f;
            if (tg < NS) {
                float srcp = ((float)tg + 0.5f)*(1.0f/256.0f) - 0.5f;
                srcp = fminf(fmaxf(srcp, 0.f), 127.f);
                int i0 = (int)srcp;
                float fr = srcp - (float)i0;
                int i1 = i0 + 1; if (i1 > 127) i1 = 127;
                e = envl[i0]*(1.f-fr) + envl[i1]*fr;
            }
            re[w] = imp[w]*e + carry[w];
            im[w] = 0.f;
        }
        __syncthreads();
        fft512(re, im, twr, twi, tid, false);
        {
            const float* tp = tfT + ((size_t)ev*128 + f)*514;
            int k = tid;
            float xr = re[k], xi = im[k];
            float tr = tp[2*k], ti = tp[2*k+1];
            float sr = xr*tr - xi*ti;
            float si = xr*ti + xi*tr;
            if (k == 0) si = 0.f;
            re[k] = sr; im[k] = si;
            if (k >= 1) { re[512-k] = sr; im[512-k] = -si; }
            if (tid == 0) {
                float xr2 = re[256], xi2 = im[256];
                float sr2 = xr2*tp[512] - xi2*tp[513];
                re[256] = sr2; im[256] = 0.f;
            }
        }
        __syncthreads();
        fft512(re, im, twr, twi, tid, true);
        float o0 = re[tid]     * inv512 * ham[tid];
        float o1 = re[tid+256] * inv512 * ham[tid+256];
        atoms[(size_t)ev*NS + f*256 + tid] = o0 + acc[tid];
        acc[tid] = o1;
        carry[tid] = o0;
        carry[tid+256] = o1;
        __syncthreads();
    }
}

// ---------------- final = sum_a values[a]*atoms[a, t-idx[a]] ----------------
__global__ void k_gather(const float* __restrict__ atoms, const float* __restrict__ topv,
                         const int* __restrict__ topi, float* __restrict__ fin)
{
    int b = blockIdx.y;
    int t = blockIdx.x*256 + threadIdx.x;
    float s = 0.f;
    for (int a = 0; a < 32; ++a) {
        int ii = topi[b*32 + a];
        if (ii <= t) s += topv[b*32 + a] * atoms[(size_t)(b*32 + a)*NS + (t - ii)];
    }
    fin[b*NS + t] = s;
}

// ---------------- wet = final (*) ir (causal direct conv), out = m*wet + final*(1-m) ----------------
__global__ __launch_bounds__(256) void k_wet(const float* __restrict__ fin, const float* __restrict__ ir,
    const float* __restrict__ mval, float* __restrict__ out)
{
    int b = blockIdx.y;
    int t0 = blockIdx.x*256;
    int tid = threadIdx.x;
    __shared__ float fs[256];
    __shared__ float irw[512];
    float wet = 0.f;
    for (int c0 = 0; c0 <= t0; c0 += 256) {
        __syncthreads();
        fs[tid] = fin[b*NS + c0 + tid];
        int dmin = t0 - c0 - 255;
        for (int q = tid; q < 511; q += 256) {
            int dd = dmin + q;
            irw[q] = ((unsigned)dd < NS) ? ir[b*NS + dd] : 0.f;
        }
        __syncthreads();
        if (c0 < t0) {
            #pragma unroll 8
            for (int k = 0; k < 256; ++k) wet += fs[k]*irw[tid + 255 - k];
        } else {
            for (int k = 0; k <= tid; ++k) wet += fs[k]*irw[tid + 255 - k];
        }
    }
    float m = mval[b];
    float fv = fin[b*NS + t0 + tid];
    out[b*NS + t0 + tid] = m*wet + fv*(1.f - m);
}

extern "C" void kernel_launch(void* const* d_in, const int* in_sizes, int n_in,
                              void* d_out, int out_size, void* d_ws, size_t ws_size,
                              hipStream_t stream)
{
    (void)in_sizes; (void)n_in; (void)out_size; (void)ws_size;
    const float* x    = (const float*)d_in[0];
    const float* fbw  = (const float*)d_in[1];
    const float* dsw  = (const float*)d_in[2];
    const float* dsb  = (const float*)d_in[3];
    const float* dgw  = (const float*)d_in[4];
    const float* dgb  = (const float*)d_in[5];
    const float* dow  = (const float*)d_in[6];
    const float* dob  = (const float*)d_in[7];
    const float* dnw  = (const float*)d_in[8];
    const float* dnb  = (const float*)d_in[9];
    const float* elw  = (const float*)d_in[10];
    const float* elb  = (const float*)d_in[11];
    const float* ecw  = (const float*)d_in[12];
    const float* ecb  = (const float*)d_in[13];
    const float* efw  = (const float*)d_in[14];
    const float* efb  = (const float*)d_in[15];
    const float* tlw  = (const float*)d_in[16];
    const float* tlb  = (const float*)d_in[17];
    const float* tcw  = (const float*)d_in[18];
    const float* tcb  = (const float*)d_in[19];
    const float* tfw  = (const float*)d_in[20];
    const float* tfb  = (const float*)d_in[21];
    const float* iw   = (const float*)d_in[22];
    const float* ib   = (const float*)d_in[23];
    const float* iow  = (const float*)d_in[24];
    const float* iob  = (const float*)d_in[25];
    const float* rw   = (const float*)d_in[26];
    const float* rb   = (const float*)d_in[27];
    const float* row_ = (const float*)d_in[28];
    const float* rob  = (const float*)d_in[29];
    const float* mw   = (const float*)d_in[30];
    const float* mb   = (const float*)d_in[31];
    const float* mow  = (const float*)d_in[32];
    const float* mob  = (const float*)d_in[33];
    const float* rooms= (const float*)d_in[34];
    const float* noise= (const float*)d_in[35];

    float* ws   = (float*)d_ws;
    float* n0   = ws;                       // 16,777,216
    float* n1   = ws + 16777216;            // 16,777,216
    float* accb = ws + 33554432;            // 16,777,216
    float* wT   = ws + 50331648;            // 1,376,256
    float* woT  = ws + 51707904;            // 114,688
    float* wnT  = ws + 51822592;            // 114,688
    float* envsq= ws + 51937280;            // 16,384
    float* lat  = ws + 51953664;            // 16,384
    float* itfb = ws + 51970048;            // 65,792
    float* norms= ws + 52035840;            // 131,072
    float* topv = ws + 52166912;            // 128
    int*   topi = (int*)(ws + 52167040);    // 128
    float* agg  = ws + 52167168;            // 512
    float* probs= ws + 52167680;            // 32
    float* mval = ws + 52167712;            // 32
    float* irb  = ws + 52167744;            // 131,072
    float* fin  = ws + 52298816;            // 131,072
    float* tfT  = n0;                        // reuse after dilated stack is done
    float* atoms= n0 + 8421376;              // reuse (8.42M + 4.19M < 16.77M)
    float* wtu  = n1;                        // 393,216  (n1 free after stack)
    float* wtf  = n1 + 393216;               // 199,680

    float* out = (float*)d_out;

    k_wtrans<<<dim3((1376256+255)/256), dim3(256), 0, stream>>>(dsw, dgw, wT);
    k_wtrans2<<<dim3((114688+255)/256), dim3(256), 0, stream>>>(dow, dnw, woT, wnT);
    k_front<<<dim3(512,4), dim3(512), 0, stream>>>(x, fbw, n0);

    const int dil[7] = {1,3,9,27,81,243,1};
    float* cin = n0; float* cout = n1;
    for (int l = 0; l < 7; ++l) {
        k_layer<<<dim3(256,4), dim3(512), 0, stream>>>(
            cin, cout, accb, wT + l*98304,
            dsb + l*128, dgb + l*128,
            woT + l*16384, dob + l*128,
            wnT + l*16384, dnb + l*128,
            dil[l], l==0 ? 1 : 0);
        float* tmp = cin; cin = cout; cout = tmp;
    }
    k_norms<<<dim3(128,4), dim3(256), 0, stream>>>(accb, norms);
    k_topk<<<dim3(4), dim3(1024), 0, stream>>>(norms, topv, topi);
    k_latents<<<dim3(128), dim3(128), 0, stream>>>(accb, topi, lat);
    k_aggmax<<<dim3(512), dim3(256), 0, stream>>>(accb, agg);
    // n1 is dead after the stack (final n unused by the reference) -> carve conv_up weights from it
    k_wtrans_up<<<dim3(1536), dim3(256), 0, stream>>>(ecw, tcw, tfw, wtu, wtf);
    k_convup2<<<dim3(128,2), dim3(512), 0, stream>>>(lat, elw, elb, ecb, efw, efb,
                                                     tlw, tlb, tcb, tfb, wtu, wtf, envsq, tfT);
    k_itf<<<dim3(128), dim3(128), 0, stream>>>(lat, iw, ib, iow, iob, itfb);
    k_roommix<<<dim3(4), dim3(128), 0, stream>>>(agg, rw, rb, row_, rob, mw, mb, mow, mob, probs, mval);
    k_ir<<<dim3(128,4), dim3(256), 0, stream>>>(probs, rooms, irb);
    k_event<<<dim3(128), dim3(256), 0, stream>>>(tfT, itfb, envsq, noise, atoms);
    k_gather<<<dim3(128,4), dim3(256), 0, stream>>>(atoms, topv, topi, fin);
    k_wet<<<dim3(128,4), dim3(256), 0, stream>>>(fin, irb, mval, out);
}

// Round 6
// 12800.928 us; speedup vs baseline: 7.0306x; 7.0306x over previous
//
#include <hip/hip_runtime.h>
#include <math.h>

#define NS 32768

static __device__ __forceinline__ float leakyf(float x){ return x >= 0.f ? x : 0.2f*x; }

// ---------------- weight transpose for dilated stack: wT[l][sg][j][cc][o] ----------------
__global__ void k_wtrans(const float* __restrict__ ws, const float* __restrict__ wg, float* __restrict__ wT)
{
    int idx = blockIdx.x*256 + threadIdx.x;
    const int total = 7*2*3*128*128;
    if (idx >= total) return;
    int o  = idx & 127;
    int cc = (idx >> 7) & 127;
    int j  = (idx >> 14) % 3;
    int sg = (idx / 49152) & 1;
    int l  = idx / 98304;
    const float* src = sg ? wg : ws;
    wT[idx] = src[((l*128 + o)*128 + cc)*3 + j];
}

// ---------------- stage-2 weight transpose: woT/wnT [l][c][o] ----------------
__global__ void k_wtrans2(const float* __restrict__ wo, const float* __restrict__ wn,
                          float* __restrict__ woT, float* __restrict__ wnT)
{
    int idx = blockIdx.x*256 + threadIdx.x;
    if (idx >= 7*128*128) return;
    int o = idx & 127;
    int c = (idx >> 7) & 127;
    int l = idx >> 14;
    woT[idx] = wo[(l*128 + o)*128 + c];
    wnT[idx] = wn[(l*128 + o)*128 + c];
}

// ---------------- conv_up weight transposes ----------------
// wtu[(mode*4+layer)][c][j][o=128]   (8*128*3*128 = 393216)
// wtf[c][j][ctp=520 (zero-padded)]   (128*3*520   = 199680)
__global__ void k_wtrans_up(const float* __restrict__ ecw, const float* __restrict__ tcw,
                            const float* __restrict__ tfw, float* __restrict__ wtu, float* __restrict__ wtf)
{
    int idx = blockIdx.x*256 + threadIdx.x;
    if (idx < 393216) {
        int o = idx & 127;
        int j = (idx >> 7) % 3;
        int c = (idx / 384) & 127;
        int ml = idx / 49152;
        const float* src = (ml < 4 ? ecw : tcw) + (ml & 3)*49152;
        wtu[idx] = src[(o*128 + c)*3 + j];
    }
    if (idx < 199680) {
        int ct = idx % 520;
        int j = (idx / 520) % 3;
        int c = idx / 1560;
        wtf[idx] = (ct < 514) ? tfw[(ct*128 + c)*3 + j] : 0.f;
    }
}

// ---------------- front conv: n[b,c,t] = sum_k x[b, t+k-256] * fbw[c,k] ----------------
__global__ __launch_bounds__(512) void k_front(const float* __restrict__ x, const float* __restrict__ fbw,
                                               float* __restrict__ n0)
{
    int b = blockIdx.y;
    int t0 = blockIdx.x * 64;
    int tid = threadIdx.x;
    int t = tid & 63, og = tid >> 6;
    __shared__ float xs[576];
    __shared__ float4 wl[2048]; // [c][k4] 64 k per chunk
    for (int i = tid; i < 575; i += 512) {
        int p = t0 + i - 256;
        xs[i] = ((unsigned)p < NS) ? x[b*NS + p] : 0.f;
    }
    float s[16];
    #pragma unroll
    for (int i = 0; i < 16; ++i) s[i] = 0.f;
    for (int kc = 0; kc < 8; ++kc) {
        __syncthreads();
        for (int i = tid; i < 2048; i += 512) {
            int c = i >> 4, k4 = i & 15;
            wl[i] = *(const float4*)(fbw + c*512 + kc*64 + k4*4);
        }
        __syncthreads();
        for (int k4 = 0; k4 < 16; ++k4) {
            int base = t + kc*64 + k4*4;
            float xv0 = xs[base+0], xv1 = xs[base+1], xv2 = xs[base+2], xv3 = xs[base+3];
            #pragma unroll
            for (int i = 0; i < 16; ++i) {
                float4 w = wl[(og*16 + i)*16 + k4];
                s[i] += w.x*xv0 + w.y*xv1 + w.z*xv2 + w.w*xv3;
            }
        }
    }
    #pragma unroll
    for (int i = 0; i < 16; ++i)
        n0[(size_t)(b*128 + og*16 + i)*NS + t0 + t] = s[i];
}

// ---------------- one dilated gated layer (LDS-staged, double-buffered weights) ----------------
// pool layout (floats):
//   stage 1: ns[3][128][64] @0 (24576) | wbuf[2][2sg][3j][8cc][128o] @24576, @30720 (6144 each)
//   stage 2: h[128][64] @0 (8192)      | w2buf[2][2arm][32cc][128o]  @8192, @16384 (8192 each)
__global__ __launch_bounds__(512) void k_layer(const float* __restrict__ nin, float* __restrict__ nout,
        float* __restrict__ acc, const float* __restrict__ wTl,
        const float* __restrict__ bs, const float* __restrict__ bg,
        const float* __restrict__ woTl, const float* __restrict__ bo,
        const float* __restrict__ wnTl, const float* __restrict__ bn,
        int d, int first)
{
    __shared__ float pool[36864]; // 144 KB
    int b = blockIdx.y;
    int t0 = blockIdx.x * 64;
    int tid = threadIdx.x;
    int t = tid & 63, og = tid >> 6;
    const float* nb = nin + (size_t)b*128*NS;

    // stage ns[3][128][64]: j strips at t0 + (j-1)*d
    for (int k = tid; k < 24576; k += 512) {
        int j  = k >> 13;
        int c  = (k >> 6) & 127;
        int tt = k & 63;
        int p  = t0 + tt + (j-1)*d;
        pool[k] = ((unsigned)p < NS) ? nb[(size_t)c*NS + p] : 0.f;
    }

    // preload stage-1 weight chunk 0 (cc 0..7) into regs
    const float4* wg4 = (const float4*)wTl;
    float4 wreg[3];
    #pragma unroll
    for (int i = 0; i < 3; ++i) {
        int idx4 = tid + i*512;
        int sg = idx4/768, j = (idx4/256)%3, rest = idx4%256;
        wreg[i] = wg4[((sg*3+j)*128 + 0)*32 + rest];
    }

    float s[16], g[16];
    #pragma unroll
    for (int i = 0; i < 16; ++i) { int o = og*16+i; s[i] = bs[o]; g[i] = bg[o]; }

    for (int cb = 0; cb < 16; ++cb) {
        int cur = cb & 1;
        float4* wb4 = (float4*)(pool + 24576 + cur*6144);
        #pragma unroll
        for (int i = 0; i < 3; ++i) wb4[tid + i*512] = wreg[i];
        if (cb < 15) {
            int cc0n = (cb+1)*8;
            #pragma unroll
            for (int i = 0; i < 3; ++i) {
                int idx4 = tid + i*512;
                int sg = idx4/768, j = (idx4/256)%3, rest = idx4%256;
                wreg[i] = wg4[((sg*3+j)*128 + cc0n)*32 + rest];
            }
        }
        __syncthreads();
        int cc0 = cb*8;
        const float4* wsb = (const float4*)(pool + 24576 + cur*6144);
        for (int ccx = 0; ccx < 8; ++ccx) {
            int cc = cc0 + ccx;
            float nv0 = pool[        cc*64 + t];
            float nv1 = pool[ 8192 + cc*64 + t];
            float nv2 = pool[16384 + cc*64 + t];
            #pragma unroll
            for (int j = 0; j < 3; ++j) {
                float nv = (j==0) ? nv0 : ((j==1) ? nv1 : nv2);
                const float4* ws4 = wsb + j*256 + ccx*32 + og*4;
                const float4* wgg = ws4 + 768;
                #pragma unroll
                for (int i4 = 0; i4 < 4; ++i4) {
                    float4 a4 = ws4[i4], b4 = wgg[i4];
                    s[i4*4+0] += nv*a4.x; s[i4*4+1] += nv*a4.y;
                    s[i4*4+2] += nv*a4.z; s[i4*4+3] += nv*a4.w;
                    g[i4*4+0] += nv*b4.x; g[i4*4+1] += nv*b4.y;
                    g[i4*4+2] += nv*b4.z; g[i4*4+3] += nv*b4.w;
                }
            }
        }
    }

    // gated activation + skip grab (skip = nin[o][t0+t] = ns[1][o][t], still live)
    float hv[16], sk[16];
    #pragma unroll
    for (int i = 0; i < 16; ++i) {
        hv[i] = tanhf(s[i]) * (1.f/(1.f + __expf(-g[i])));
        sk[i] = pool[8192 + (og*16+i)*64 + t];
    }
    __syncthreads();   // all stage-1 reads of pool done before overwrite
    #pragma unroll
    for (int i = 0; i < 16; ++i) pool[(og*16+i)*64 + t] = hv[i];

    // preload stage-2 weight chunk 0 (cc 0..31)
    float4 wreg2[4];
    #pragma unroll
    for (int i = 0; i < 4; ++i) {
        int idx4 = tid + i*512;
        int arm = idx4 >> 10, rest = idx4 & 1023;
        const float4* src = (const float4*)(arm ? wnTl : woTl);
        wreg2[i] = src[rest];
    }

    float a[16], nn[16];
    #pragma unroll
    for (int i = 0; i < 16; ++i) { a[i] = 0.f; nn[i] = 0.f; }

    for (int cb2 = 0; cb2 < 4; ++cb2) {
        int cur = cb2 & 1;
        float4* w2b = (float4*)(pool + 8192 + cur*8192);
        #pragma unroll
        for (int i = 0; i < 4; ++i) w2b[tid + i*512] = wreg2[i];
        if (cb2 < 3) {
            int cc0n = (cb2+1)*32;
            #pragma unroll
            for (int i = 0; i < 4; ++i) {
                int idx4 = tid + i*512;
                int arm = idx4 >> 10, rest = idx4 & 1023;
                const float4* src = (const float4*)(arm ? wnTl : woTl);
                wreg2[i] = src[cc0n*32 + rest];
            }
        }
        __syncthreads();
        const float4* rb4 = (const float4*)(pool + 8192 + cur*8192);
        for (int cc = 0; cc < 32; ++cc) {
            float hvv = pool[(cb2*32 + cc)*64 + t];
            const float4* wo4 = rb4 + cc*32 + og*4;
            const float4* wn4 = wo4 + 1024;
            #pragma unroll
            for (int i4 = 0; i4 < 4; ++i4) {
                float4 w0 = wo4[i4], w1 = wn4[i4];
                a[i4*4+0]  += hvv*w0.x; a[i4*4+1]  += hvv*w0.y;
                a[i4*4+2]  += hvv*w0.z; a[i4*4+3]  += hvv*w0.w;
                nn[i4*4+0] += hvv*w1.x; nn[i4*4+1] += hvv*w1.y;
                nn[i4*4+2] += hvv*w1.z; nn[i4*4+3] += hvv*w1.w;
            }
        }
    }

    #pragma unroll
    for (int i = 0; i < 16; ++i) {
        int o = og*16 + i;
        size_t gi = (size_t)(b*128 + o)*NS + t0 + t;
        float av = first ? 0.f : acc[gi];
        acc[gi] = av + a[i] + bo[o];
        nout[gi] = nn[i] + bn[o] + sk[i];
    }
}

// ---------------- norms^2 over channels ----------------
__global__ void k_norms(const float* __restrict__ xf, float* __restrict__ norms)
{
    int b = blockIdx.y;
    int t = blockIdx.x*256 + threadIdx.x;
    float a = 0.f;
    for (int c = 0; c < 128; ++c) {
        float v = xf[(size_t)(b*128 + c)*NS + t];
        a += v*v;
    }
    norms[b*NS + t] = a;
}

// ---------------- top-32 per batch (destroys norms) ----------------
__global__ __launch_bounds__(1024) void k_topk(float* __restrict__ norms, float* __restrict__ topv, int* __restrict__ topi)
{
    int b = blockIdx.x;
    int tid = threadIdx.x;
    __shared__ float rv[1024];
    __shared__ int   ri[1024];
    for (int it = 0; it < 32; ++it) {
        float best = -2.f; int bi = 0;
        for (int k = tid; k < NS; k += 1024) {
            float v = norms[b*NS + k];
            if (v > best) { best = v; bi = k; }
        }
        rv[tid] = best; ri[tid] = bi;
        __syncthreads();
        for (int off = 512; off > 0; off >>= 1) {
            if (tid < off) {
                float ov = rv[tid+off]; int oi = ri[tid+off];
                if (ov > rv[tid] || (ov == rv[tid] && oi < ri[tid])) { rv[tid] = ov; ri[tid] = oi; }
            }
            __syncthreads();
        }
        if (tid == 0) {
            topv[b*32 + it] = sqrtf(rv[0]);
            topi[b*32 + it] = ri[0];
            norms[b*NS + ri[0]] = -1.f;
        }
        __syncthreads();
    }
}

// ---------------- gather latents ----------------
__global__ void k_latents(const float* __restrict__ xf, const int* __restrict__ topi, float* __restrict__ lat)
{
    int ev = blockIdx.x; int c = threadIdx.x;
    int b = ev >> 5;
    int idx = topi[ev];
    lat[ev*128 + c] = xf[(size_t)(b*128 + c)*NS + idx];
}

// ---------------- agg = max over time ----------------
__global__ void k_aggmax(const float* __restrict__ xf, float* __restrict__ agg)
{
    int rc = blockIdx.x;
    int tid = threadIdx.x;
    __shared__ float red[256];
    float m = -3.4e38f;
    const float* row = xf + (size_t)rc*NS;
    for (int t = tid; t < NS; t += 256) m = fmaxf(m, row[t]);
    red[tid] = m; __syncthreads();
    for (int off = 128; off > 0; off >>= 1) {
        if (tid < off) red[tid] = fmaxf(red[tid], red[tid+off]);
        __syncthreads();
    }
    if (tid == 0) agg[rc] = red[0];
}

// ---------------- generic upsample layer: repeat(2) + conv3(pad1) + leaky ----------------
template<int L2>
__device__ __forceinline__ void up_layer(const float* __restrict__ wbase, const float* __restrict__ bias,
                                         const float* __restrict__ inb, float* __restrict__ outb,
                                         float* __restrict__ wst, int tid)
{
    constexpr int NO  = L2/4;
    constexpr int Lin = L2/2;
    constexpr int LOG = (L2==16)?4:(L2==32)?5:6;
    int p  = tid & (L2-1);
    int og = tid >> LOG;
    int o0 = og*NO;
    float acc[NO];
    #pragma unroll
    for (int k = 0; k < NO; ++k) acc[k] = 0.f;
    for (int cc0 = 0; cc0 < 128; cc0 += 16) {
        __syncthreads();
        for (int k = tid; k < 6144; k += 512) wst[k] = wbase[cc0*384 + k];
        __syncthreads();
        for (int ci = 0; ci < 16; ++ci) {
            int c = cc0 + ci;
            float xv[3];
            #pragma unroll
            for (int j = 0; j < 3; ++j) {
                int iu = p + j - 1;
                xv[j] = ((unsigned)iu < (unsigned)L2) ? inb[c*Lin + (iu>>1)] : 0.f;
            }
            #pragma unroll
            for (int j = 0; j < 3; ++j) {
                const float4* w4 = (const float4*)(wst + (ci*3 + j)*128 + o0);
                #pragma unroll
                for (int q = 0; q < NO/4; ++q) {
                    float4 w = w4[q];
                    acc[q*4+0] += xv[j]*w.x; acc[q*4+1] += xv[j]*w.y;
                    acc[q*4+2] += xv[j]*w.z; acc[q*4+3] += xv[j]*w.w;
                }
            }
        }
    }
    #pragma unroll
    for (int k = 0; k < NO; ++k) outb[(o0+k)*L2 + p] = leakyf(acc[k] + bias[o0+k]);
}

// L2=128 layer in two o-halves (NO=16/thread, no spills); stages only the needed 64-o slice
__device__ __forceinline__ void up_layer128(const float* __restrict__ wbase, const float* __restrict__ bias,
                                            const float* __restrict__ inb, float* __restrict__ outb,
                                            float* __restrict__ wst, int tid, int half)
{
    int p  = tid & 127;
    int og = tid >> 7;      // 0..3
    int o0 = og*16;         // local offset within the 64-o half
    float acc[16];
    #pragma unroll
    for (int k = 0; k < 16; ++k) acc[k] = 0.f;
    for (int cc0 = 0; cc0 < 128; cc0 += 16) {
        __syncthreads();
        for (int k = tid; k < 3072; k += 512) {
            int ci = k / 192, rem = k - ci*192;
            int j = rem >> 6, o = rem & 63;
            wst[k] = wbase[(cc0+ci)*384 + j*128 + half*64 + o];
        }
        __syncthreads();
        for (int ci = 0; ci < 16; ++ci) {
            int c = cc0 + ci;
            float xv[3];
            #pragma unroll
            for (int j = 0; j < 3; ++j) {
                int iu = p + j - 1;
                xv[j] = ((unsigned)iu < 128u) ? inb[c*64 + (iu>>1)] : 0.f;
            }
            #pragma unroll
            for (int j = 0; j < 3; ++j) {
                const float4* w4 = (const float4*)(wst + ci*192 + j*64 + o0);
                #pragma unroll
                for (int q = 0; q < 4; ++q) {
                    float4 w = w4[q];
                    acc[q*4+0] += xv[j]*w.x; acc[q*4+1] += xv[j]*w.y;
                    acc[q*4+2] += xv[j]*w.z; acc[q*4+3] += xv[j]*w.w;
                }
            }
        }
    }
    #pragma unroll
    for (int k = 0; k < 16; ++k) {
        int o = half*64 + o0 + k;
        outb[o*128 + p] = leakyf(acc[k] + bias[o]);
    }
}

// ---------------- fused conv_up: gridDim=(128 events, 2 modes), 512 threads ----------------
__global__ __launch_bounds__(512) void k_convup2(const float* __restrict__ lat,
    const float* __restrict__ elw, const float* __restrict__ elb, const float* __restrict__ ecb,
    const float* __restrict__ efw, const float* __restrict__ efb,
    const float* __restrict__ tlw, const float* __restrict__ tlb, const float* __restrict__ tcb,
    const float* __restrict__ tfb, const float* __restrict__ wtu, const float* __restrict__ wtf,
    float* __restrict__ envsq, float* __restrict__ tfT)
{
    __shared__ float pool[39104]; // 152.75 KB
    float* latv = pool;           // 128
    float* bufA = pool + 128;     // 8256 (doubles as trb, stride 129)
    float* bufB = pool + 8384;    // 8192
    float* bufC = pool + 16576;   // 16384
    float* wst  = pool + 32960;   // 6144
    int ev = blockIdx.x;
    int m  = blockIdx.y;
    int tid = threadIdx.x;
    const float* lw = m ? tlw : elw;
    const float* lb = m ? tlb : elb;
    const float* cb = m ? tcb : ecb;
    const float* wu = wtu + m*4*49152;
    if (tid < 128) latv[tid] = lat[ev*128 + tid];
    __syncthreads();
    for (int jj = tid; jj < 1024; jj += 512) {
        float a = lb[jj];
        const float4* w4 = (const float4*)(lw + jj*128);
        #pragma unroll 8
        for (int q = 0; q < 32; ++q) {
            float4 w = w4[q];
            a += w.x*latv[q*4] + w.y*latv[q*4+1] + w.z*latv[q*4+2] + w.w*latv[q*4+3];
        }
        bufA[(jj>>3)*8 + (jj&7)] = a;
    }
    up_layer<16>(wu,        cb,     bufA, bufB, wst, tid);
    up_layer<32>(wu+49152,  cb+128, bufB, bufA, wst, tid);
    up_layer<64>(wu+98304,  cb+256, bufA, bufB, wst, tid);
    up_layer128(wu+147456, cb+384, bufB, bufC, wst, tid, 0);
    up_layer128(wu+147456, cb+384, bufB, bufC, wst, tid, 1);
    __syncthreads();
    int p = tid & 127, g = tid >> 7;
    if (m == 0) {
        float s = 0.f;
        for (int c = g*32; c < g*32+32; ++c) {
            #pragma unroll
            for (int j = 0; j < 3; ++j) {
                int iu = p + j - 1;
                float xv = ((unsigned)iu < 128u) ? bufC[c*128 + iu] : 0.f;
                s += efw[c*3+j]*xv;
            }
        }
        wst[g*128 + p] = s;
        __syncthreads();
        if (g == 0) {
            float a = wst[p] + wst[128+p] + wst[256+p] + wst[384+p] + efb[0];
            envsq[ev*128 + p] = a*a;
        }
    } else {
        float* trb = bufA;   // [64ct][stride 129] transpose buffer
        for (int ctb = 0; ctb < 9; ++ctb) {
            int ct0 = ctb*64;
            float acc[16];
            #pragma unroll
            for (int i = 0; i < 16; ++i) acc[i] = 0.f;
            for (int cc0 = 0; cc0 < 128; cc0 += 16) {
                __syncthreads();
                for (int k = tid; k < 3072; k += 512) {
                    int ci = k / 192, rem = k - ci*192;
                    int j = rem >> 6, ct = rem & 63;
                    wst[k] = wtf[(cc0+ci)*1560 + j*520 + ct0 + ct];
                }
                __syncthreads();
                for (int ci = 0; ci < 16; ++ci) {
                    int c = cc0 + ci;
                    float xv[3];
                    #pragma unroll
                    for (int j = 0; j < 3; ++j) {
                        int iu = p + j - 1;
                        xv[j] = ((unsigned)iu < 128u) ? bufC[c*128 + iu] : 0.f;
                    }
                    #pragma unroll
                    for (int j = 0; j < 3; ++j) {
                        const float4* w4 = (const float4*)(wst + ci*192 + j*64 + g*16);
                        #pragma unroll
                        for (int q = 0; q < 4; ++q) {
                            float4 w = w4[q];
                            acc[q*4+0] += xv[j]*w.x; acc[q*4+1] += xv[j]*w.y;
                            acc[q*4+2] += xv[j]*w.z; acc[q*4+3] += xv[j]*w.w;
                        }
                    }
                }
            }
            __syncthreads();      // previous trb consumers done
            #pragma unroll
            for (int i = 0; i < 16; ++i) trb[(g*16 + i)*129 + p] = acc[i];
            __syncthreads();
            int ctl = tid & 63, pg = tid >> 6;
            #pragma unroll
            for (int pass = 0; pass < 16; ++pass) {
                int pp = pass*8 + pg;
                int ct = ct0 + ctl;
                if (ct < 514)
                    tfT[(size_t)(ev*128 + pp)*514 + ct] = trb[ctl*129 + pp] + tfb[ct];
            }
        }
    }
}

// ---------------- impulse transfer lin_stack ----------------
__global__ __launch_bounds__(128) void k_itf(const float* __restrict__ lat,
    const float* __restrict__ iw, const float* __restrict__ ib,
    const float* __restrict__ iow, const float* __restrict__ iob,
    float* __restrict__ itf)
{
    int ev = blockIdx.x; int tid = threadIdx.x;
    __shared__ float xa[128], xb[128];
    xa[tid] = lat[ev*128 + tid];
    __syncthreads();
    float* src = xa; float* dst = xb;
    for (int l = 0; l < 3; ++l) {
        float a = ib[l*128 + tid];
        const float* wr = iw + (l*128 + tid)*128;
        for (int k = 0; k < 128; ++k) a += wr[k]*src[k];
        dst[tid] = leakyf(a);
        __syncthreads();
        float* tmp = src; src = dst; dst = tmp;
    }
    for (int o = tid; o < 514; o += 128) {
        float a = iob[o];
        const float* wr = iow + o*128;
        for (int k = 0; k < 128; ++k) a += wr[k]*src[k];
        itf[ev*514 + o] = a;
    }
}

// ---------------- room/mix lin_stacks + softmax ----------------
__global__ __launch_bounds__(128) void k_roommix(const float* __restrict__ agg,
    const float* __restrict__ rw, const float* __restrict__ rb,
    const float* __restrict__ row_, const float* __restrict__ rob,
    const float* __restrict__ mw, const float* __restrict__ mb,
    const float* __restrict__ mow, const float* __restrict__ mob,
    float* __restrict__ probs, float* __restrict__ mval)
{
    int b = blockIdx.x; int tid = threadIdx.x;
    __shared__ float xa[128], xb[128], rr[8];
    xa[tid] = agg[b*128 + tid];
    __syncthreads();
    float* src = xa; float* dst = xb;
    for (int l = 0; l < 3; ++l) {
        float a = rb[l*128 + tid];
        const float* wr = rw + (l*128 + tid)*128;
        for (int k = 0; k < 128; ++k) a += wr[k]*src[k];
        dst[tid] = leakyf(a);
        __syncthreads();
        float* tmp = src; src = dst; dst = tmp;
    }
    if (tid < 8) {
        float a = rob[tid];
        const float* wr = row_ + tid*128;
        for (int k = 0; k < 128; ++k) a += wr[k]*src[k];
        rr[tid] = a;
    }
    __syncthreads();
    if (tid == 0) {
        float m = rr[0];
        for (int j = 1; j < 8; ++j) m = fmaxf(m, rr[j]);
        float ssum = 0.f; float e[8];
        for (int j = 0; j < 8; ++j) { e[j] = __expf(rr[j]-m); ssum += e[j]; }
        for (int j = 0; j < 8; ++j) probs[b*8+j] = e[j]/ssum;
    }
    __syncthreads();
    xa[tid] = agg[b*128 + tid];
    __syncthreads();
    src = xa; dst = xb;
    for (int l = 0; l < 3; ++l) {
        float a = mb[l*128 + tid];
        const float* wr = mw + (l*128 + tid)*128;
        for (int k = 0; k < 128; ++k) a += wr[k]*src[k];
        dst[tid] = leakyf(a);
        __syncthreads();
        float* tmp = src; src = dst; dst = tmp;
    }
    if (tid == 0) {
        float a = mob[0];
        for (int k = 0; k < 128; ++k) a += mow[k]*src[k];
        mval[b] = a;
    }
}

// ---------------- ir = softmax(r) @ rooms ----------------
__global__ void k_ir(const float* __restrict__ probs, const float* __restrict__ rooms, float* __restrict__ ir)
{
    int b = blockIdx.y;
    int t = blockIdx.x*256 + threadIdx.x;
    float a = 0.f;
    for (int j = 0; j < 8; ++j) a += probs[b*8+j]*rooms[j*NS + t];
    ir[b*NS + t] = a;
}

// ---------------- 512-pt complex FFT in LDS (256 threads) ----------------
__device__ __forceinline__ void fft512(float* re, float* im, const float* twr, const float* twi, int tid, bool inverse)
{
    for (int w = tid; w < 512; w += 256) {
        unsigned r = __brev((unsigned)w) >> 23;
        if ((int)r > w) {
            float tr = re[w]; re[w] = re[r]; re[r] = tr;
            float ti = im[w]; im[w] = im[r]; im[r] = ti;
        }
    }
    __syncthreads();
    for (int s = 0; s < 9; ++s) {
        int half = 1 << s;
        int grp = tid >> s;
        int pos = tid & (half-1);
        int i0 = (grp << (s+1)) + pos;
        int i1 = i0 + half;
        int twidx = pos << (8 - s);
        float wr = twr[twidx];
        float wi = inverse ? -twi[twidx] : twi[twidx];
        float r1 = re[i1], q1 = im[i1];
        float tr = wr*r1 - wi*q1;
        float ti = wr*q1 + wi*r1;
        float r0 = re[i0], q0 = im[i0];
        re[i1] = r0 - tr; im[i1] = q0 - ti;
        re[i0] = r0 + tr; im[i0] = q0 + ti;
        __syncthreads();
    }
}

// ---------------- per-event scan: impulse -> 128 frames of env*imp + carry -> FFT filter -> OLA ----------------
__global__ __launch_bounds__(256) void k_event(const float* __restrict__ tfT, const float* __restrict__ itf,
    const float* __restrict__ envsq, const float* __restrict__ noise, float* __restrict__ atoms)
{
    int ev = blockIdx.x; int tid = threadIdx.x;
    __shared__ float twr[256], twi[256];
    __shared__ float re[512], im[512], carry[512], imp[512], ham[512], acc[256], envl[128];
    if (tid < 128) envl[tid] = envsq[ev*128 + tid];
    {
        float ang = -6.283185307179586f * (float)tid / 512.0f;
        float si, co;
        sincosf(ang, &si, &co);
        twr[tid] = co; twi[tid] = si;
    }
    for (int w = tid; w < 512; w += 256) {
        ham[w] = 0.54f - 0.46f*cosf(6.283185307179586f * (float)w / 512.0f);
        re[w] = noise[w]; im[w] = 0.f; carry[w] = 0.f;
    }
    acc[tid] = 0.f;
    __syncthreads();
    fft512(re, im, twr, twi, tid, false);
    {
        const float* tp = itf + ev*514;
        int k = tid;
        float xr = re[k], xi = im[k];
        float tr = tp[2*k], ti = tp[2*k+1];
        float sr = xr*tr - xi*ti;
        float si = xr*ti + xi*tr;
        if (k == 0) si = 0.f;
        re[k] = sr; im[k] = si;
        if (k >= 1) { re[512-k] = sr; im[512-k] = -si; }
        if (tid == 0) {
            float xr2 = re[256], xi2 = im[256];
            float sr2 = xr2*tp[512] - xi2*tp[513];
            re[256] = sr2; im[256] = 0.f;
        }
    }
    __syncthreads();
    fft512(re, im, twr, twi, tid, true);
    for (int w = tid; w < 512; w += 256) imp[w] = re[w] * (1.0f/512.0f);
    __syncthreads();
    const float inv512 = 1.0f/512.0f;
    for (int f = 0; f < 128; ++f) {
        for (int w = tid; w < 512; w += 256) {
            int tg = f*256 + w;
            float e = 0.f;
            if (tg < NS) {
                float srcp = ((float)tg + 0.5f)*(1.0f/256.0f) - 0.5f;
                srcp = fminf(fmaxf(srcp, 0.f), 127.f);
                int i0 = (int)srcp;
                float fr = srcp - (float)i0;
                int i1 = i0 + 1; if (i1 > 127) i1 = 127;
                e = envl[i0]*(1.f-fr) + envl[i1]*fr;
            }
            re[w] = imp[w]*e + carry[w];
            im[w] = 0.f;
        }
        __syncthreads();
        fft512(re, im, twr, twi, tid, false);
        {
            const float* tp = tfT + ((size_t)ev*128 + f)*514;
            int k = tid;
            float xr = re[k], xi = im[k];
            float tr = tp[2*k], ti = tp[2*k+1];
            float sr = xr*tr - xi*ti;
            float si = xr*ti + xi*tr;
            if (k == 0) si = 0.f;
            re[k] = sr; im[k] = si;
            if (k >= 1) { re[512-k] = sr; im[512-k] = -si; }
            if (tid == 0) {
                float xr2 = re[256], xi2 = im[256];
                float sr2 = xr2*tp[512] - xi2*tp[513];
                re[256] = sr2; im[256] = 0.f;
            }
        }
        __syncthreads();
        fft512(re, im, twr, twi, tid, true);
        float o0 = re[tid]     * inv512 * ham[tid];
        float o1 = re[tid+256] * inv512 * ham[tid+256];
        atoms[(size_t)ev*NS + f*256 + tid] = o0 + acc[tid];
        acc[tid] = o1;
        carry[tid] = o0;
        carry[tid+256] = o1;
        __syncthreads();
    }
}

// ---------------- final = sum_a values[a]*atoms[a, t-idx[a]] ----------------
__global__ void k_gather(const float* __restrict__ atoms, const float* __restrict__ topv,
                         const int* __restrict__ topi, float* __restrict__ fin)
{
    int b = blockIdx.y;
    int t = blockIdx.x*256 + threadIdx.x;
    float s = 0.f;
    for (int a = 0; a < 32; ++a) {
        int ii = topi[b*32 + a];
        if (ii <= t) s += topv[b*32 + a] * atoms[(size_t)(b*32 + a)*NS + (t - ii)];
    }
    fin[b*NS + t] = s;
}

// ---------------- wet = final (*) ir (causal direct conv), out = m*wet + final*(1-m) ----------------
__global__ __launch_bounds__(256) void k_wet(const float* __restrict__ fin, const float* __restrict__ ir,
    const float* __restrict__ mval, float* __restrict__ out)
{
    int b = blockIdx.y;
    int t0 = blockIdx.x*256;
    int tid = threadIdx.x;
    __shared__ float fs[256];
    __shared__ float irw[512];
    float wet = 0.f;
    for (int c0 = 0; c0 <= t0; c0 += 256) {
        __syncthreads();
        fs[tid] = fin[b*NS + c0 + tid];
        int dmin = t0 - c0 - 255;
        for (int q = tid; q < 511; q += 256) {
            int dd = dmin + q;
            irw[q] = ((unsigned)dd < NS) ? ir[b*NS + dd] : 0.f;
        }
        __syncthreads();
        if (c0 < t0) {
            #pragma unroll 8
            for (int k = 0; k < 256; ++k) wet += fs[k]*irw[tid + 255 - k];
        } else {
            for (int k = 0; k <= tid; ++k) wet += fs[k]*irw[tid + 255 - k];
        }
    }
    float m = mval[b];
    float fv = fin[b*NS + t0 + tid];
    out[b*NS + t0 + tid] = m*wet + fv*(1.f - m);
}

extern "C" void kernel_launch(void* const* d_in, const int* in_sizes, int n_in,
                              void* d_out, int out_size, void* d_ws, size_t ws_size,
                              hipStream_t stream)
{
    (void)in_sizes; (void)n_in; (void)out_size; (void)ws_size;
    const float* x    = (const float*)d_in[0];
    const float* fbw  = (const float*)d_in[1];
    const float* dsw  = (const float*)d_in[2];
    const float* dsb  = (const float*)d_in[3];
    const float* dgw  = (const float*)d_in[4];
    const float* dgb  = (const float*)d_in[5];
    const float* dow  = (const float*)d_in[6];
    const float* dob  = (const float*)d_in[7];
    const float* dnw  = (const float*)d_in[8];
    const float* dnb  = (const float*)d_in[9];
    const float* elw  = (const float*)d_in[10];
    const float* elb  = (const float*)d_in[11];
    const float* ecw  = (const float*)d_in[12];
    const float* ecb  = (const float*)d_in[13];
    const float* efw  = (const float*)d_in[14];
    const float* efb  = (const float*)d_in[15];
    const float* tlw  = (const float*)d_in[16];
    const float* tlb  = (const float*)d_in[17];
    const float* tcw  = (const float*)d_in[18];
    const float* tcb  = (const float*)d_in[19];
    const float* tfw  = (const float*)d_in[20];
    const float* tfb  = (const float*)d_in[21];
    const float* iw   = (const float*)d_in[22];
    const float* ib   = (const float*)d_in[23];
    const float* iow  = (const float*)d_in[24];
    const float* iob  = (const float*)d_in[25];
    const float* rw   = (const float*)d_in[26];
    const float* rb   = (const float*)d_in[27];
    const float* row_ = (const float*)d_in[28];
    const float* rob  = (const float*)d_in[29];
    const float* mw   = (const float*)d_in[30];
    const float* mb   = (const float*)d_in[31];
    const float* mow  = (const float*)d_in[32];
    const float* mob  = (const float*)d_in[33];
    const float* rooms= (const float*)d_in[34];
    const float* noise= (const float*)d_in[35];

    float* ws   = (float*)d_ws;
    float* n0   = ws;                       // 16,777,216
    float* n1   = ws + 16777216;            // 16,777,216
    float* accb = ws + 33554432;            // 16,777,216
    float* wT   = ws + 50331648;            // 1,376,256
    float* woT  = ws + 51707904;            // 114,688
    float* wnT  = ws + 51822592;            // 114,688
    float* envsq= ws + 51937280;            // 16,384
    float* lat  = ws + 51953664;            // 16,384
    float* itfb = ws + 51970048;            // 65,792
    float* norms= ws + 52035840;            // 131,072
    float* topv = ws + 52166912;            // 128
    int*   topi = (int*)(ws + 52167040);    // 128
    float* agg  = ws + 52167168;            // 512
    float* probs= ws + 52167680;            // 32
    float* mval = ws + 52167712;            // 32
    float* irb  = ws + 52167744;            // 131,072
    float* fin  = ws + 52298816;            // 131,072
    float* tfT  = n0;                        // reuse after dilated stack is done
    float* atoms= n0 + 8421376;              // reuse (8.42M + 4.19M < 16.77M)
    float* wtu  = n1;                        // 393,216  (n1 free after stack)
    float* wtf  = n1 + 393216;               // 199,680

    float* out = (float*)d_out;

    k_wtrans<<<dim3((1376256+255)/256), dim3(256), 0, stream>>>(dsw, dgw, wT);
    k_wtrans2<<<dim3((114688+255)/256), dim3(256), 0, stream>>>(dow, dnw, woT, wnT);
    k_front<<<dim3(512,4), dim3(512), 0, stream>>>(x, fbw, n0);

    const int dil[7] = {1,3,9,27,81,243,1};
    float* cin = n0; float* cout = n1;
    for (int l = 0; l < 7; ++l) {
        k_layer<<<dim3(512,4), dim3(512), 0, stream>>>(
            cin, cout, accb, wT + l*98304,
            dsb + l*128, dgb + l*128,
            woT + l*16384, dob + l*128,
            wnT + l*16384, dnb + l*128,
            dil[l], l==0 ? 1 : 0);
        float* tmp = cin; cin = cout; cout = tmp;
    }
    k_norms<<<dim3(128,4), dim3(256), 0, stream>>>(accb, norms);
    k_topk<<<dim3(4), dim3(1024), 0, stream>>>(norms, topv, topi);
    k_latents<<<dim3(128), dim3(128), 0, stream>>>(accb, topi, lat);
    k_aggmax<<<dim3(512), dim3(256), 0, stream>>>(accb, agg);
    // n1 is dead after the stack (final n unused by the reference) -> carve conv_up weights from it
    k_wtrans_up<<<dim3(1536), dim3(256), 0, stream>>>(ecw, tcw, tfw, wtu, wtf);
    k_convup2<<<dim3(128,2), dim3(512), 0, stream>>>(lat, elw, elb, ecb, efw, efb,
                                                     tlw, tlb, tcb, tfb, wtu, wtf, envsq, tfT);
    k_itf<<<dim3(128), dim3(128), 0, stream>>>(lat, iw, ib, iow, iob, itfb);
    k_roommix<<<dim3(4), dim3(128), 0, stream>>>(agg, rw, rb, row_, rob, mw, mb, mow, mob, probs, mval);
    k_ir<<<dim3(128,4), dim3(256), 0, stream>>>(probs, rooms, irb);
    k_event<<<dim3(128), dim3(256), 0, stream>>>(tfT, itfb, envsq, noise, atoms);
    k_gather<<<dim3(128,4), dim3(256), 0, stream>>>(atoms, topv, topi, fin);
    k_wet<<<dim3(128,4), dim3(256), 0, stream>>>(fin, irb, mval, out);
}

// Round 7
// 12787.938 us; speedup vs baseline: 7.0377x; 1.0010x over previous
//
#include <hip/hip_runtime.h>
#include <math.h>

#define NS 32768

static __device__ __forceinline__ float leakyf(float x){ return x >= 0.f ? x : 0.2f*x; }

// ---------------- weight transpose for dilated stack: wT[l][sg][j][cc][o] ----------------
__global__ void k_wtrans(const float* __restrict__ ws, const float* __restrict__ wg, float* __restrict__ wT)
{
    int idx = blockIdx.x*256 + threadIdx.x;
    const int total = 7*2*3*128*128;
    if (idx >= total) return;
    int o  = idx & 127;
    int cc = (idx >> 7) & 127;
    int j  = (idx >> 14) % 3;
    int sg = (idx / 49152) & 1;
    int l  = idx / 98304;
    const float* src = sg ? wg : ws;
    wT[idx] = src[((l*128 + o)*128 + cc)*3 + j];
}

// ---------------- stage-2 weight transpose: woT/wnT [l][c][o] ----------------
__global__ void k_wtrans2(const float* __restrict__ wo, const float* __restrict__ wn,
                          float* __restrict__ woT, float* __restrict__ wnT)
{
    int idx = blockIdx.x*256 + threadIdx.x;
    if (idx >= 7*128*128) return;
    int o = idx & 127;
    int c = (idx >> 7) & 127;
    int l = idx >> 14;
    woT[idx] = wo[(l*128 + o)*128 + c];
    wnT[idx] = wn[(l*128 + o)*128 + c];
}

// ---------------- conv_up weight transposes ----------------
// wtu[(mode*4+layer)][c][j][o=128]   (8*128*3*128 = 393216)
// wtf[c][j][ctp=520 (zero-padded)]   (128*3*520   = 199680)
__global__ void k_wtrans_up(const float* __restrict__ ecw, const float* __restrict__ tcw,
                            const float* __restrict__ tfw, float* __restrict__ wtu, float* __restrict__ wtf)
{
    int idx = blockIdx.x*256 + threadIdx.x;
    if (idx < 393216) {
        int o = idx & 127;
        int j = (idx >> 7) % 3;
        int c = (idx / 384) & 127;
        int ml = idx / 49152;
        const float* src = (ml < 4 ? ecw : tcw) + (ml & 3)*49152;
        wtu[idx] = src[(o*128 + c)*3 + j];
    }
    if (idx < 199680) {
        int ct = idx % 520;
        int j = (idx / 520) % 3;
        int c = idx / 1560;
        wtf[idx] = (ct < 514) ? tfw[(ct*128 + c)*3 + j] : 0.f;
    }
}

// ---------------- front conv: n[b,c,t] = sum_k x[b, t+k-256] * fbw[c,k] ----------------
__global__ __launch_bounds__(512) void k_front(const float* __restrict__ x, const float* __restrict__ fbw,
                                               float* __restrict__ n0)
{
    int b = blockIdx.y;
    int t0 = blockIdx.x * 64;
    int tid = threadIdx.x;
    int t = tid & 63, og = tid >> 6;
    __shared__ float xs[576];
    __shared__ float4 wl[2048]; // [c][k4] 64 k per chunk
    for (int i = tid; i < 575; i += 512) {
        int p = t0 + i - 256;
        xs[i] = ((unsigned)p < NS) ? x[b*NS + p] : 0.f;
    }
    float s[16];
    #pragma unroll
    for (int i = 0; i < 16; ++i) s[i] = 0.f;
    for (int kc = 0; kc < 8; ++kc) {
        __syncthreads();
        for (int i = tid; i < 2048; i += 512) {
            int c = i >> 4, k4 = i & 15;
            wl[i] = *(const float4*)(fbw + c*512 + kc*64 + k4*4);
        }
        __syncthreads();
        for (int k4 = 0; k4 < 16; ++k4) {
            int base = t + kc*64 + k4*4;
            float xv0 = xs[base+0], xv1 = xs[base+1], xv2 = xs[base+2], xv3 = xs[base+3];
            #pragma unroll
            for (int i = 0; i < 16; ++i) {
                float4 w = wl[(og*16 + i)*16 + k4];
                s[i] += w.x*xv0 + w.y*xv1 + w.z*xv2 + w.w*xv3;
            }
        }
    }
    #pragma unroll
    for (int i = 0; i < 16; ++i)
        n0[(size_t)(b*128 + og*16 + i)*NS + t0 + t] = s[i];
}

// ---------------- one dilated gated layer (LDS-staged, double-buffered weights) ----------------
// pool layout (floats):
//   stage 1: ns[3][128][64] @0 (24576) | wbuf[2][2sg][3j][8cc][128o] @24576, @30720 (6144 each)
//   stage 2: h[128][64] @0 (8192)      | w2buf[2][2arm][32cc][128o]  @8192, @16384 (8192 each)
__global__ __launch_bounds__(512) void k_layer(const float* __restrict__ nin, float* __restrict__ nout,
        float* __restrict__ acc, const float* __restrict__ wTl,
        const float* __restrict__ bs, const float* __restrict__ bg,
        const float* __restrict__ woTl, const float* __restrict__ bo,
        const float* __restrict__ wnTl, const float* __restrict__ bn,
        int d, int first)
{
    __shared__ float pool[36864]; // 144 KB
    int b = blockIdx.y;
    int t0 = blockIdx.x * 64;
    int tid = threadIdx.x;
    int t = tid & 63, og = tid >> 6;
    const float* nb = nin + (size_t)b*128*NS;

    // stage ns[3][128][64]: j strips at t0 + (j-1)*d
    for (int k = tid; k < 24576; k += 512) {
        int j  = k >> 13;
        int c  = (k >> 6) & 127;
        int tt = k & 63;
        int p  = t0 + tt + (j-1)*d;
        pool[k] = ((unsigned)p < NS) ? nb[(size_t)c*NS + p] : 0.f;
    }

    // preload stage-1 weight chunk 0 (cc 0..7) into regs
    const float4* wg4 = (const float4*)wTl;
    float4 wreg[3];
    #pragma unroll
    for (int i = 0; i < 3; ++i) {
        int idx4 = tid + i*512;
        int sg = idx4/768, j = (idx4/256)%3, rest = idx4%256;
        wreg[i] = wg4[((sg*3+j)*128 + 0)*32 + rest];
    }

    float s[16], g[16];
    #pragma unroll
    for (int i = 0; i < 16; ++i) { int o = og*16+i; s[i] = bs[o]; g[i] = bg[o]; }

    for (int cb = 0; cb < 16; ++cb) {
        int cur = cb & 1;
        float4* wb4 = (float4*)(pool + 24576 + cur*6144);
        #pragma unroll
        for (int i = 0; i < 3; ++i) wb4[tid + i*512] = wreg[i];
        if (cb < 15) {
            int cc0n = (cb+1)*8;
            #pragma unroll
            for (int i = 0; i < 3; ++i) {
                int idx4 = tid + i*512;
                int sg = idx4/768, j = (idx4/256)%3, rest = idx4%256;
                wreg[i] = wg4[((sg*3+j)*128 + cc0n)*32 + rest];
            }
        }
        __syncthreads();
        int cc0 = cb*8;
        const float4* wsb = (const float4*)(pool + 24576 + cur*6144);
        for (int ccx = 0; ccx < 8; ++ccx) {
            int cc = cc0 + ccx;
            float nv0 = pool[        cc*64 + t];
            float nv1 = pool[ 8192 + cc*64 + t];
            float nv2 = pool[16384 + cc*64 + t];
            #pragma unroll
            for (int j = 0; j < 3; ++j) {
                float nv = (j==0) ? nv0 : ((j==1) ? nv1 : nv2);
                const float4* ws4 = wsb + j*256 + ccx*32 + og*4;
                const float4* wgg = ws4 + 768;
                #pragma unroll
                for (int i4 = 0; i4 < 4; ++i4) {
                    float4 a4 = ws4[i4], b4 = wgg[i4];
                    s[i4*4+0] += nv*a4.x; s[i4*4+1] += nv*a4.y;
                    s[i4*4+2] += nv*a4.z; s[i4*4+3] += nv*a4.w;
                    g[i4*4+0] += nv*b4.x; g[i4*4+1] += nv*b4.y;
                    g[i4*4+2] += nv*b4.z; g[i4*4+3] += nv*b4.w;
                }
            }
        }
    }

    // gated activation + skip grab (skip = nin[o][t0+t] = ns[1][o][t], still live)
    float hv[16], sk[16];
    #pragma unroll
    for (int i = 0; i < 16; ++i) {
        hv[i] = tanhf(s[i]) * (1.f/(1.f + __expf(-g[i])));
        sk[i] = pool[8192 + (og*16+i)*64 + t];
    }
    __syncthreads();   // all stage-1 reads of pool done before overwrite
    #pragma unroll
    for (int i = 0; i < 16; ++i) pool[(og*16+i)*64 + t] = hv[i];

    // preload stage-2 weight chunk 0 (cc 0..31)
    float4 wreg2[4];
    #pragma unroll
    for (int i = 0; i < 4; ++i) {
        int idx4 = tid + i*512;
        int arm = idx4 >> 10, rest = idx4 & 1023;
        const float4* src = (const float4*)(arm ? wnTl : woTl);
        wreg2[i] = src[rest];
    }

    float a[16], nn[16];
    #pragma unroll
    for (int i = 0; i < 16; ++i) { a[i] = 0.f; nn[i] = 0.f; }

    for (int cb2 = 0; cb2 < 4; ++cb2) {
        int cur = cb2 & 1;
        float4* w2b = (float4*)(pool + 8192 + cur*8192);
        #pragma unroll
        for (int i = 0; i < 4; ++i) w2b[tid + i*512] = wreg2[i];
        if (cb2 < 3) {
            int cc0n = (cb2+1)*32;
            #pragma unroll
            for (int i = 0; i < 4; ++i) {
                int idx4 = tid + i*512;
                int arm = idx4 >> 10, rest = idx4 & 1023;
                const float4* src = (const float4*)(arm ? wnTl : woTl);
                wreg2[i] = src[cc0n*32 + rest];
            }
        }
        __syncthreads();
        const float4* rb4 = (const float4*)(pool + 8192 + cur*8192);
        for (int cc = 0; cc < 32; ++cc) {
            float hvv = pool[(cb2*32 + cc)*64 + t];
            const float4* wo4 = rb4 + cc*32 + og*4;
            const float4* wn4 = wo4 + 1024;
            #pragma unroll
            for (int i4 = 0; i4 < 4; ++i4) {
                float4 w0 = wo4[i4], w1 = wn4[i4];
                a[i4*4+0]  += hvv*w0.x; a[i4*4+1]  += hvv*w0.y;
                a[i4*4+2]  += hvv*w0.z; a[i4*4+3]  += hvv*w0.w;
                nn[i4*4+0] += hvv*w1.x; nn[i4*4+1] += hvv*w1.y;
                nn[i4*4+2] += hvv*w1.z; nn[i4*4+3] += hvv*w1.w;
            }
        }
    }

    #pragma unroll
    for (int i = 0; i < 16; ++i) {
        int o = og*16 + i;
        size_t gi = (size_t)(b*128 + o)*NS + t0 + t;
        float av = first ? 0.f : acc[gi];
        acc[gi] = av + a[i] + bo[o];
        nout[gi] = nn[i] + bn[o] + sk[i];
    }
}

// ---------------- norms^2 over channels ----------------
__global__ void k_norms(const float* __restrict__ xf, float* __restrict__ norms)
{
    int b = blockIdx.y;
    int t = blockIdx.x*256 + threadIdx.x;
    float a = 0.f;
    for (int c = 0; c < 128; ++c) {
        float v = xf[(size_t)(b*128 + c)*NS + t];
        a += v*v;
    }
    norms[b*NS + t] = a;
}

// ---------------- top-32 per batch (destroys norms) ----------------
__global__ __launch_bounds__(1024) void k_topk(float* __restrict__ norms, float* __restrict__ topv, int* __restrict__ topi)
{
    int b = blockIdx.x;
    int tid = threadIdx.x;
    __shared__ float rv[1024];
    __shared__ int   ri[1024];
    for (int it = 0; it < 32; ++it) {
        float best = -2.f; int bi = 0;
        for (int k = tid; k < NS; k += 1024) {
            float v = norms[b*NS + k];
            if (v > best) { best = v; bi = k; }
        }
        rv[tid] = best; ri[tid] = bi;
        __syncthreads();
        for (int off = 512; off > 0; off >>= 1) {
            if (tid < off) {
                float ov = rv[tid+off]; int oi = ri[tid+off];
                if (ov > rv[tid] || (ov == rv[tid] && oi < ri[tid])) { rv[tid] = ov; ri[tid] = oi; }
            }
            __syncthreads();
        }
        if (tid == 0) {
            topv[b*32 + it] = sqrtf(rv[0]);
            topi[b*32 + it] = ri[0];
            norms[b*NS + ri[0]] = -1.f;
        }
        __syncthreads();
    }
}

// ---------------- gather latents ----------------
__global__ void k_latents(const float* __restrict__ xf, const int* __restrict__ topi, float* __restrict__ lat)
{
    int ev = blockIdx.x; int c = threadIdx.x;
    int b = ev >> 5;
    int idx = topi[ev];
    lat[ev*128 + c] = xf[(size_t)(b*128 + c)*NS + idx];
}

// ---------------- agg = max over time ----------------
__global__ void k_aggmax(const float* __restrict__ xf, float* __restrict__ agg)
{
    int rc = blockIdx.x;
    int tid = threadIdx.x;
    __shared__ float red[256];
    float m = -3.4e38f;
    const float* row = xf + (size_t)rc*NS;
    for (int t = tid; t < NS; t += 256) m = fmaxf(m, row[t]);
    red[tid] = m; __syncthreads();
    for (int off = 128; off > 0; off >>= 1) {
        if (tid < off) red[tid] = fmaxf(red[tid], red[tid+off]);
        __syncthreads();
    }
    if (tid == 0) agg[rc] = red[0];
}

// ---------------- generic upsample layer: repeat(2) + conv3(pad1) + leaky ----------------
template<int L2>
__device__ __forceinline__ void up_layer(const float* __restrict__ wbase, const float* __restrict__ bias,
                                         const float* __restrict__ inb, float* __restrict__ outb,
                                         float* __restrict__ wst, int tid)
{
    constexpr int NO  = L2/4;
    constexpr int Lin = L2/2;
    constexpr int LOG = (L2==16)?4:(L2==32)?5:6;
    int p  = tid & (L2-1);
    int og = tid >> LOG;
    int o0 = og*NO;
    float acc[NO];
    #pragma unroll
    for (int k = 0; k < NO; ++k) acc[k] = 0.f;
    for (int cc0 = 0; cc0 < 128; cc0 += 16) {
        __syncthreads();
        for (int k = tid; k < 6144; k += 512) wst[k] = wbase[cc0*384 + k];
        __syncthreads();
        for (int ci = 0; ci < 16; ++ci) {
            int c = cc0 + ci;
            float xv[3];
            #pragma unroll
            for (int j = 0; j < 3; ++j) {
                int iu = p + j - 1;
                xv[j] = ((unsigned)iu < (unsigned)L2) ? inb[c*Lin + (iu>>1)] : 0.f;
            }
            #pragma unroll
            for (int j = 0; j < 3; ++j) {
                const float4* w4 = (const float4*)(wst + (ci*3 + j)*128 + o0);
                #pragma unroll
                for (int q = 0; q < NO/4; ++q) {
                    float4 w = w4[q];
                    acc[q*4+0] += xv[j]*w.x; acc[q*4+1] += xv[j]*w.y;
                    acc[q*4+2] += xv[j]*w.z; acc[q*4+3] += xv[j]*w.w;
                }
            }
        }
    }
    #pragma unroll
    for (int k = 0; k < NO; ++k) outb[(o0+k)*L2 + p] = leakyf(acc[k] + bias[o0+k]);
}

// L2=128 layer in two o-halves (NO=16/thread, no spills); stages only the needed 64-o slice
__device__ __forceinline__ void up_layer128(const float* __restrict__ wbase, const float* __restrict__ bias,
                                            const float* __restrict__ inb, float* __restrict__ outb,
                                            float* __restrict__ wst, int tid, int half)
{
    int p  = tid & 127;
    int og = tid >> 7;      // 0..3
    int o0 = og*16;         // local offset within the 64-o half
    float acc[16];
    #pragma unroll
    for (int k = 0; k < 16; ++k) acc[k] = 0.f;
    for (int cc0 = 0; cc0 < 128; cc0 += 16) {
        __syncthreads();
        for (int k = tid; k < 3072; k += 512) {
            int ci = k / 192, rem = k - ci*192;
            int j = rem >> 6, o = rem & 63;
            wst[k] = wbase[(cc0+ci)*384 + j*128 + half*64 + o];
        }
        __syncthreads();
        for (int ci = 0; ci < 16; ++ci) {
            int c = cc0 + ci;
            float xv[3];
            #pragma unroll
            for (int j = 0; j < 3; ++j) {
                int iu = p + j - 1;
                xv[j] = ((unsigned)iu < 128u) ? inb[c*64 + (iu>>1)] : 0.f;
            }
            #pragma unroll
            for (int j = 0; j < 3; ++j) {
                const float4* w4 = (const float4*)(wst + ci*192 + j*64 + o0);
                #pragma unroll
                for (int q = 0; q < 4; ++q) {
                    float4 w = w4[q];
                    acc[q*4+0] += xv[j]*w.x; acc[q*4+1] += xv[j]*w.y;
                    acc[q*4+2] += xv[j]*w.z; acc[q*4+3] += xv[j]*w.w;
                }
            }
        }
    }
    #pragma unroll
    for (int k = 0; k < 16; ++k) {
        int o = half*64 + o0 + k;
        outb[o*128 + p] = leakyf(acc[k] + bias[o]);
    }
}

// ---------------- fused conv_up: gridDim=(128 events, 2 modes), 512 threads ----------------
// LDS 153KB -> 1 block/CU (2 waves/SIMD). min-blocks=1 lets the allocator use up to 256 VGPR
// (default target was 128 -> massive scratch spill, 8GB writes/dispatch in r6).
__global__ __launch_bounds__(512, 1) void k_convup2(const float* __restrict__ lat,
    const float* __restrict__ elw, const float* __restrict__ elb, const float* __restrict__ ecb,
    const float* __restrict__ efw, const float* __restrict__ efb,
    const float* __restrict__ tlw, const float* __restrict__ tlb, const float* __restrict__ tcb,
    const float* __restrict__ tfb, const float* __restrict__ wtu, const float* __restrict__ wtf,
    float* __restrict__ envsq, float* __restrict__ tfT)
{
    __shared__ float pool[39104]; // 152.75 KB
    float* latv = pool;           // 128
    float* bufA = pool + 128;     // 8256 (doubles as trb, stride 129)
    float* bufB = pool + 8384;    // 8192
    float* bufC = pool + 16576;   // 16384
    float* wst  = pool + 32960;   // 6144
    int ev = blockIdx.x;
    int m  = blockIdx.y;
    int tid = threadIdx.x;
    const float* lw = m ? tlw : elw;
    const float* lb = m ? tlb : elb;
    const float* cb = m ? tcb : ecb;
    const float* wu = wtu + m*4*49152;
    if (tid < 128) latv[tid] = lat[ev*128 + tid];
    __syncthreads();
    for (int jj = tid; jj < 1024; jj += 512) {
        float a = lb[jj];
        const float4* w4 = (const float4*)(lw + jj*128);
        #pragma unroll 8
        for (int q = 0; q < 32; ++q) {
            float4 w = w4[q];
            a += w.x*latv[q*4] + w.y*latv[q*4+1] + w.z*latv[q*4+2] + w.w*latv[q*4+3];
        }
        bufA[(jj>>3)*8 + (jj&7)] = a;
    }
    up_layer<16>(wu,        cb,     bufA, bufB, wst, tid);
    up_layer<32>(wu+49152,  cb+128, bufB, bufA, wst, tid);
    up_layer<64>(wu+98304,  cb+256, bufA, bufB, wst, tid);
    up_layer128(wu+147456, cb+384, bufB, bufC, wst, tid, 0);
    up_layer128(wu+147456, cb+384, bufB, bufC, wst, tid, 1);
    __syncthreads();
    int p = tid & 127, g = tid >> 7;
    if (m == 0) {
        float s = 0.f;
        for (int c = g*32; c < g*32+32; ++c) {
            #pragma unroll
            for (int j = 0; j < 3; ++j) {
                int iu = p + j - 1;
                float xv = ((unsigned)iu < 128u) ? bufC[c*128 + iu] : 0.f;
                s += efw[c*3+j]*xv;
            }
        }
        wst[g*128 + p] = s;
        __syncthreads();
        if (g == 0) {
            float a = wst[p] + wst[128+p] + wst[256+p] + wst[384+p] + efb[0];
            envsq[ev*128 + p] = a*a;
        }
    } else {
        float* trb = bufA;   // [64ct][stride 129] transpose buffer
        for (int ctb = 0; ctb < 9; ++ctb) {
            int ct0 = ctb*64;
            float acc[16];
            #pragma unroll
            for (int i = 0; i < 16; ++i) acc[i] = 0.f;
            for (int cc0 = 0; cc0 < 128; cc0 += 16) {
                __syncthreads();
                for (int k = tid; k < 3072; k += 512) {
                    int ci = k / 192, rem = k - ci*192;
                    int j = rem >> 6, ct = rem & 63;
                    wst[k] = wtf[(cc0+ci)*1560 + j*520 + ct0 + ct];
                }
                __syncthreads();
                for (int ci = 0; ci < 16; ++ci) {
                    int c = cc0 + ci;
                    float xv[3];
                    #pragma unroll
                    for (int j = 0; j < 3; ++j) {
                        int iu = p + j - 1;
                        xv[j] = ((unsigned)iu < 128u) ? bufC[c*128 + iu] : 0.f;
                    }
                    #pragma unroll
                    for (int j = 0; j < 3; ++j) {
                        const float4* w4 = (const float4*)(wst + ci*192 + j*64 + g*16);
                        #pragma unroll
                        for (int q = 0; q < 4; ++q) {
                            float4 w = w4[q];
                            acc[q*4+0] += xv[j]*w.x; acc[q*4+1] += xv[j]*w.y;
                            acc[q*4+2] += xv[j]*w.z; acc[q*4+3] += xv[j]*w.w;
                        }
                    }
                }
            }
            __syncthreads();      // previous trb consumers done
            #pragma unroll
            for (int i = 0; i < 16; ++i) trb[(g*16 + i)*129 + p] = acc[i];
            __syncthreads();
            int ctl = tid & 63, pg = tid >> 6;
            #pragma unroll
            for (int pass = 0; pass < 16; ++pass) {
                int pp = pass*8 + pg;
                int ct = ct0 + ctl;
                if (ct < 514)
                    tfT[(size_t)(ev*128 + pp)*514 + ct] = trb[ctl*129 + pp] + tfb[ct];
            }
        }
    }
}

// ---------------- impulse transfer lin_stack ----------------
__global__ __launch_bounds__(128) void k_itf(const float* __restrict__ lat,
    const float* __restrict__ iw, const float* __restrict__ ib,
    const float* __restrict__ iow, const float* __restrict__ iob,
    float* __restrict__ itf)
{
    int ev = blockIdx.x; int tid = threadIdx.x;
    __shared__ float xa[128], xb[128];
    xa[tid] = lat[ev*128 + tid];
    __syncthreads();
    float* src = xa; float* dst = xb;
    for (int l = 0; l < 3; ++l) {
        float a = ib[l*128 + tid];
        const float* wr = iw + (l*128 + tid)*128;
        for (int k = 0; k < 128; ++k) a += wr[k]*src[k];
        dst[tid] = leakyf(a);
        __syncthreads();
        float* tmp = src; src = dst; dst = tmp;
    }
    for (int o = tid; o < 514; o += 128) {
        float a = iob[o];
        const float* wr = iow + o*128;
        for (int k = 0; k < 128; ++k) a += wr[k]*src[k];
        itf[ev*514 + o] = a;
    }
}

// ---------------- room/mix lin_stacks + softmax ----------------
__global__ __launch_bounds__(128) void k_roommix(const float* __restrict__ agg,
    const float* __restrict__ rw, const float* __restrict__ rb,
    const float* __restrict__ row_, const float* __restrict__ rob,
    const float* __restrict__ mw, const float* __restrict__ mb,
    const float* __restrict__ mow, const float* __restrict__ mob,
    float* __restrict__ probs, float* __restrict__ mval)
{
    int b = blockIdx.x; int tid = threadIdx.x;
    __shared__ float xa[128], xb[128], rr[8];
    xa[tid] = agg[b*128 + tid];
    __syncthreads();
    float* src = xa; float* dst = xb;
    for (int l = 0; l < 3; ++l) {
        float a = rb[l*128 + tid];
        const float* wr = rw + (l*128 + tid)*128;
        for (int k = 0; k < 128; ++k) a += wr[k]*src[k];
        dst[tid] = leakyf(a);
        __syncthreads();
        float* tmp = src; src = dst; dst = tmp;
    }
    if (tid < 8) {
        float a = rob[tid];
        const float* wr = row_ + tid*128;
        for (int k = 0; k < 128; ++k) a += wr[k]*src[k];
        rr[tid] = a;
    }
    __syncthreads();
    if (tid == 0) {
        float m = rr[0];
        for (int j = 1; j < 8; ++j) m = fmaxf(m, rr[j]);
        float ssum = 0.f; float e[8];
        for (int j = 0; j < 8; ++j) { e[j] = __expf(rr[j]-m); ssum += e[j]; }
        for (int j = 0; j < 8; ++j) probs[b*8+j] = e[j]/ssum;
    }
    __syncthreads();
    xa[tid] = agg[b*128 + tid];
    __syncthreads();
    src = xa; dst = xb;
    for (int l = 0; l < 3; ++l) {
        float a = mb[l*128 + tid];
        const float* wr = mw + (l*128 + tid)*128;
        for (int k = 0; k < 128; ++k) a += wr[k]*src[k];
        dst[tid] = leakyf(a);
        __syncthreads();
        float* tmp = src; src = dst; dst = tmp;
    }
    if (tid == 0) {
        float a = mob[0];
        for (int k = 0; k < 128; ++k) a += mow[k]*src[k];
        mval[b] = a;
    }
}

// ---------------- ir = softmax(r) @ rooms ----------------
__global__ void k_ir(const float* __restrict__ probs, const float* __restrict__ rooms, float* __restrict__ ir)
{
    int b = blockIdx.y;
    int t = blockIdx.x*256 + threadIdx.x;
    float a = 0.f;
    for (int j = 0; j < 8; ++j) a += probs[b*8+j]*rooms[j*NS + t];
    ir[b*NS + t] = a;
}

// ---------------- 512-pt complex FFT in LDS (256 threads) ----------------
__device__ __forceinline__ void fft512(float* re, float* im, const float* twr, const float* twi, int tid, bool inverse)
{
    for (int w = tid; w < 512; w += 256) {
        unsigned r = __brev((unsigned)w) >> 23;
        if ((int)r > w) {
            float tr = re[w]; re[w] = re[r]; re[r] = tr;
            float ti = im[w]; im[w] = im[r]; im[r] = ti;
        }
    }
    __syncthreads();
    for (int s = 0; s < 9; ++s) {
        int half = 1 << s;
        int grp = tid >> s;
        int pos = tid & (half-1);
        int i0 = (grp << (s+1)) + pos;
        int i1 = i0 + half;
        int twidx = pos << (8 - s);
        float wr = twr[twidx];
        float wi = inverse ? -twi[twidx] : twi[twidx];
        float r1 = re[i1], q1 = im[i1];
        float tr = wr*r1 - wi*q1;
        float ti = wr*q1 + wi*r1;
        float r0 = re[i0], q0 = im[i0];
        re[i1] = r0 - tr; im[i1] = q0 - ti;
        re[i0] = r0 + tr; im[i0] = q0 + ti;
        __syncthreads();
    }
}

// ---------------- per-event scan: impulse -> 128 frames of env*imp + carry -> FFT filter -> OLA ----------------
__global__ __launch_bounds__(256) void k_event(const float* __restrict__ tfT, const float* __restrict__ itf,
    const float* __restrict__ envsq, const float* __restrict__ noise, float* __restrict__ atoms)
{
    int ev = blockIdx.x; int tid = threadIdx.x;
    __shared__ float twr[256], twi[256];
    __shared__ float re[512], im[512], carry[512], imp[512], ham[512], acc[256], envl[128];
    if (tid < 128) envl[tid] = envsq[ev*128 + tid];
    {
        float ang = -6.283185307179586f * (float)tid / 512.0f;
        float si, co;
        sincosf(ang, &si, &co);
        twr[tid] = co; twi[tid] = si;
    }
    for (int w = tid; w < 512; w += 256) {
        ham[w] = 0.54f - 0.46f*cosf(6.283185307179586f * (float)w / 512.0f);
        re[w] = noise[w]; im[w] = 0.f; carry[w] = 0.f;
    }
    acc[tid] = 0.f;
    __syncthreads();
    fft512(re, im, twr, twi, tid, false);
    {
        const float* tp = itf + ev*514;
        int k = tid;
        float xr = re[k], xi = im[k];
        float tr = tp[2*k], ti = tp[2*k+1];
        float sr = xr*tr - xi*ti;
        float si = xr*ti + xi*tr;
        if (k == 0) si = 0.f;
        re[k] = sr; im[k] = si;
        if (k >= 1) { re[512-k] = sr; im[512-k] = -si; }
        if (tid == 0) {
            float xr2 = re[256], xi2 = im[256];
            float sr2 = xr2*tp[512] - xi2*tp[513];
            re[256] = sr2; im[256] = 0.f;
        }
    }
    __syncthreads();
    fft512(re, im, twr, twi, tid, true);
    for (int w = tid; w < 512; w += 256) imp[w] = re[w] * (1.0f/512.0f);
    __syncthreads();
    const float inv512 = 1.0f/512.0f;
    for (int f = 0; f < 128; ++f) {
        for (int w = tid; w < 512; w += 256) {
            int tg = f*256 + w;
            float e = 0.f;
            if (tg < NS) {
                float srcp = ((float)tg + 0.5f)*(1.0f/256.0f) - 0.5f;
                srcp = fminf(fmaxf(srcp, 0.f), 127.f);
                int i0 = (int)srcp;
                float fr = srcp - (float)i0;
                int i1 = i0 + 1; if (i1 > 127) i1 = 127;
                e = envl[i0]*(1.f-fr) + envl[i1]*fr;
            }
            re[w] = imp[w]*e + carry[w];
            im[w] = 0.f;
        }
        __syncthreads();
        fft512(re, im, twr, twi, tid, false);
        {
            const float* tp = tfT + ((size_t)ev*128 + f)*514;
            int k = tid;
            float xr = re[k], xi = im[k];
            float tr = tp[2*k], ti = tp[2*k+1];
            float sr = xr*tr - xi*ti;
            float si = xr*ti + xi*tr;
            if (k == 0) si = 0.f;
            re[k] = sr; im[k] = si;
            if (k >= 1) { re[512-k] = sr; im[512-k] = -si; }
            if (tid == 0) {
                float xr2 = re[256], xi2 = im[256];
                float sr2 = xr2*tp[512] - xi2*tp[513];
                re[256] = sr2; im[256] = 0.f;
            }
        }
        __syncthreads();
        fft512(re, im, twr, twi, tid, true);
        float o0 = re[tid]     * inv512 * ham[tid];
        float o1 = re[tid+256] * inv512 * ham[tid+256];
        atoms[(size_t)ev*NS + f*256 + tid] = o0 + acc[tid];
        acc[tid] = o1;
        carry[tid] = o0;
        carry[tid+256] = o1;
        __syncthreads();
    }
}

// ---------------- final = sum_a values[a]*atoms[a, t-idx[a]] ----------------
__global__ void k_gather(const float* __restrict__ atoms, const float* __restrict__ topv,
                         const int* __restrict__ topi, float* __restrict__ fin)
{
    int b = blockIdx.y;
    int t = blockIdx.x*256 + threadIdx.x;
    float s = 0.f;
    for (int a = 0; a < 32; ++a) {
        int ii = topi[b*32 + a];
        if (ii <= t) s += topv[b*32 + a] * atoms[(size_t)(b*32 + a)*NS + (t - ii)];
    }
    fin[b*NS + t] = s;
}

// ---------------- wet = final (*) ir (causal direct conv), out = m*wet + final*(1-m) ----------------
__global__ __launch_bounds__(256) void k_wet(const float* __restrict__ fin, const float* __restrict__ ir,
    const float* __restrict__ mval, float* __restrict__ out)
{
    int b = blockIdx.y;
    int t0 = blockIdx.x*256;
    int tid = threadIdx.x;
    __shared__ float fs[256];
    __shared__ float irw[512];
    float wet = 0.f;
    for (int c0 = 0; c0 <= t0; c0 += 256) {
        __syncthreads();
        fs[tid] = fin[b*NS + c0 + tid];
        int dmin = t0 - c0 - 255;
        for (int q = tid; q < 511; q += 256) {
            int dd = dmin + q;
            irw[q] = ((unsigned)dd < NS) ? ir[b*NS + dd] : 0.f;
        }
        __syncthreads();
        if (c0 < t0) {
            #pragma unroll 8
            for (int k = 0; k < 256; ++k) wet += fs[k]*irw[tid + 255 - k];
        } else {
            for (int k = 0; k <= tid; ++k) wet += fs[k]*irw[tid + 255 - k];
        }
    }
    float m = mval[b];
    float fv = fin[b*NS + t0 + tid];
    out[b*NS + t0 + tid] = m*wet + fv*(1.f - m);
}

extern "C" void kernel_launch(void* const* d_in, const int* in_sizes, int n_in,
                              void* d_out, int out_size, void* d_ws, size_t ws_size,
                              hipStream_t stream)
{
    (void)in_sizes; (void)n_in; (void)out_size; (void)ws_size;
    const float* x    = (const float*)d_in[0];
    const float* fbw  = (const float*)d_in[1];
    const float* dsw  = (const float*)d_in[2];
    const float* dsb  = (const float*)d_in[3];
    const float* dgw  = (const float*)d_in[4];
    const float* dgb  = (const float*)d_in[5];
    const float* dow  = (const float*)d_in[6];
    const float* dob  = (const float*)d_in[7];
    const float* dnw  = (const float*)d_in[8];
    const float* dnb  = (const float*)d_in[9];
    const float* elw  = (const float*)d_in[10];
    const float* elb  = (const float*)d_in[11];
    const float* ecw  = (const float*)d_in[12];
    const float* ecb  = (const float*)d_in[13];
    const float* efw  = (const float*)d_in[14];
    const float* efb  = (const float*)d_in[15];
    const float* tlw  = (const float*)d_in[16];
    const float* tlb  = (const float*)d_in[17];
    const float* tcw  = (const float*)d_in[18];
    const float* tcb  = (const float*)d_in[19];
    const float* tfw  = (const float*)d_in[20];
    const float* tfb  = (const float*)d_in[21];
    const float* iw   = (const float*)d_in[22];
    const float* ib   = (const float*)d_in[23];
    const float* iow  = (const float*)d_in[24];
    const float* iob  = (const float*)d_in[25];
    const float* rw   = (const float*)d_in[26];
    const float* rb   = (const float*)d_in[27];
    const float* row_ = (const float*)d_in[28];
    const float* rob  = (const float*)d_in[29];
    const float* mw   = (const float*)d_in[30];
    const float* mb   = (const float*)d_in[31];
    const float* mow  = (const float*)d_in[32];
    const float* mob  = (const float*)d_in[33];
    const float* rooms= (const float*)d_in[34];
    const float* noise= (const float*)d_in[35];

    float* ws   = (float*)d_ws;
    float* n0   = ws;                       // 16,777,216
    float* n1   = ws + 16777216;            // 16,777,216
    float* accb = ws + 33554432;            // 16,777,216
    float* wT   = ws + 50331648;            // 1,376,256
    float* woT  = ws + 51707904;            // 114,688
    float* wnT  = ws + 51822592;            // 114,688
    float* envsq= ws + 51937280;            // 16,384
    float* lat  = ws + 51953664;            // 16,384
    float* itfb = ws + 51970048;            // 65,792
    float* norms= ws + 52035840;            // 131,072
    float* topv = ws + 52166912;            // 128
    int*   topi = (int*)(ws + 52167040);    // 128
    float* agg  = ws + 52167168;            // 512
    float* probs= ws + 52167680;            // 32
    float* mval = ws + 52167712;            // 32
    float* irb  = ws + 52167744;            // 131,072
    float* fin  = ws + 52298816;            // 131,072
    float* tfT  = n0;                        // reuse after dilated stack is done
    float* atoms= n0 + 8421376;              // reuse (8.42M + 4.19M < 16.77M)
    float* wtu  = n1;                        // 393,216  (n1 free after stack)
    float* wtf  = n1 + 393216;               // 199,680

    float* out = (float*)d_out;

    k_wtrans<<<dim3((1376256+255)/256), dim3(256), 0, stream>>>(dsw, dgw, wT);
    k_wtrans2<<<dim3((114688+255)/256), dim3(256), 0, stream>>>(dow, dnw, woT, wnT);
    k_front<<<dim3(512,4), dim3(512), 0, stream>>>(x, fbw, n0);

    const int dil[7] = {1,3,9,27,81,243,1};
    float* cin = n0; float* cout = n1;
    for (int l = 0; l < 7; ++l) {
        k_layer<<<dim3(512,4), dim3(512), 0, stream>>>(
            cin, cout, accb, wT + l*98304,
            dsb + l*128, dgb + l*128,
            woT + l*16384, dob + l*128,
            wnT + l*16384, dnb + l*128,
            dil[l], l==0 ? 1 : 0);
        float* tmp = cin; cin = cout; cout = tmp;
    }
    k_norms<<<dim3(128,4), dim3(256), 0, stream>>>(accb, norms);
    k_topk<<<dim3(4), dim3(1024), 0, stream>>>(norms, topv, topi);
    k_latents<<<dim3(128), dim3(128), 0, stream>>>(accb, topi, lat);
    k_aggmax<<<dim3(512), dim3(256), 0, stream>>>(accb, agg);
    // n1 is dead after the stack (final n unused by the reference) -> carve conv_up weights from it
    k_wtrans_up<<<dim3(1536), dim3(256), 0, stream>>>(ecw, tcw, tfw, wtu, wtf);
    k_convup2<<<dim3(128,2), dim3(512), 0, stream>>>(lat, elw, elb, ecb, efw, efb,
                                                     tlw, tlb, tcb, tfb, wtu, wtf, envsq, tfT);
    k_itf<<<dim3(128), dim3(128), 0, stream>>>(lat, iw, ib, iow, iob, itfb);
    k_roommix<<<dim3(4), dim3(128), 0, stream>>>(agg, rw, rb, row_, rob, mw, mb, mow, mob, probs, mval);
    k_ir<<<dim3(128,4), dim3(256), 0, stream>>>(probs, rooms, irb);
    k_event<<<dim3(128), dim3(256), 0, stream>>>(tfT, itfb, envsq, noise, atoms);
    k_gather<<<dim3(128,4), dim3(256), 0, stream>>>(atoms, topv, topi, fin);
    k_wet<<<dim3(128,4), dim3(256), 0, stream>>>(fin, irb, mval, out);
}

// Round 8
// 10767.426 us; speedup vs baseline: 8.3584x; 1.1877x over previous
//
#include <hip/hip_runtime.h>
#include <math.h>

#define NS 32768

static __device__ __forceinline__ float leakyf(float x){ return x >= 0.f ? x : 0.2f*x; }

// ---------------- weight transpose for dilated stack: wT[l][sg][j][cc][o] ----------------
__global__ void k_wtrans(const float* __restrict__ ws, const float* __restrict__ wg, float* __restrict__ wT)
{
    int idx = blockIdx.x*256 + threadIdx.x;
    const int total = 7*2*3*128*128;
    if (idx >= total) return;
    int o  = idx & 127;
    int cc = (idx >> 7) & 127;
    int j  = (idx >> 14) % 3;
    int sg = (idx / 49152) & 1;
    int l  = idx / 98304;
    const float* src = sg ? wg : ws;
    wT[idx] = src[((l*128 + o)*128 + cc)*3 + j];
}

// ---------------- stage-2 weight transpose: woT/wnT [l][c][o] ----------------
__global__ void k_wtrans2(const float* __restrict__ wo, const float* __restrict__ wn,
                          float* __restrict__ woT, float* __restrict__ wnT)
{
    int idx = blockIdx.x*256 + threadIdx.x;
    if (idx >= 7*128*128) return;
    int o = idx & 127;
    int c = (idx >> 7) & 127;
    int l = idx >> 14;
    woT[idx] = wo[(l*128 + o)*128 + c];
    wnT[idx] = wn[(l*128 + o)*128 + c];
}

// ---------------- conv_up weight transposes ----------------
// wtu[(mode*4+layer)][c][j][o=128]   (8*128*3*128 = 393216)
// wtf[c][j][ctp=544 (zero-padded)]   (128*3*544   = 208896)
__global__ void k_wtrans_up(const float* __restrict__ ecw, const float* __restrict__ tcw,
                            const float* __restrict__ tfw, float* __restrict__ wtu, float* __restrict__ wtf)
{
    int idx = blockIdx.x*256 + threadIdx.x;
    if (idx < 393216) {
        int o = idx & 127;
        int j = (idx >> 7) % 3;
        int c = (idx / 384) & 127;
        int ml = idx / 49152;
        const float* src = (ml < 4 ? ecw : tcw) + (ml & 3)*49152;
        wtu[idx] = src[(o*128 + c)*3 + j];
    }
    if (idx < 208896) {
        int ct = idx % 544;
        int j = (idx / 544) % 3;
        int c = idx / 1632;
        wtf[idx] = (ct < 514) ? tfw[(ct*128 + c)*3 + j] : 0.f;
    }
}

// ---------------- front conv: n[b,c,t] = sum_k x[b, t+k-256] * fbw[c,k] ----------------
__global__ __launch_bounds__(512) void k_front(const float* __restrict__ x, const float* __restrict__ fbw,
                                               float* __restrict__ n0)
{
    int b = blockIdx.y;
    int t0 = blockIdx.x * 64;
    int tid = threadIdx.x;
    int t = tid & 63, og = tid >> 6;
    __shared__ float xs[576];
    __shared__ float4 wl[2048]; // [c][k4] 64 k per chunk
    for (int i = tid; i < 575; i += 512) {
        int p = t0 + i - 256;
        xs[i] = ((unsigned)p < NS) ? x[b*NS + p] : 0.f;
    }
    float s[16];
    #pragma unroll
    for (int i = 0; i < 16; ++i) s[i] = 0.f;
    for (int kc = 0; kc < 8; ++kc) {
        __syncthreads();
        for (int i = tid; i < 2048; i += 512) {
            int c = i >> 4, k4 = i & 15;
            wl[i] = *(const float4*)(fbw + c*512 + kc*64 + k4*4);
        }
        __syncthreads();
        for (int k4 = 0; k4 < 16; ++k4) {
            int base = t + kc*64 + k4*4;
            float xv0 = xs[base+0], xv1 = xs[base+1], xv2 = xs[base+2], xv3 = xs[base+3];
            #pragma unroll
            for (int i = 0; i < 16; ++i) {
                float4 w = wl[(og*16 + i)*16 + k4];
                s[i] += w.x*xv0 + w.y*xv1 + w.z*xv2 + w.w*xv3;
            }
        }
    }
    #pragma unroll
    for (int i = 0; i < 16; ++i)
        n0[(size_t)(b*128 + og*16 + i)*NS + t0 + t] = s[i];
}

// ---------------- one dilated gated layer (LDS-staged, double-buffered weights) ----------------
__global__ __launch_bounds__(512) void k_layer(const float* __restrict__ nin, float* __restrict__ nout,
        float* __restrict__ acc, const float* __restrict__ wTl,
        const float* __restrict__ bs, const float* __restrict__ bg,
        const float* __restrict__ woTl, const float* __restrict__ bo,
        const float* __restrict__ wnTl, const float* __restrict__ bn,
        int d, int first)
{
    __shared__ float pool[36864]; // 144 KB
    int b = blockIdx.y;
    int t0 = blockIdx.x * 64;
    int tid = threadIdx.x;
    int t = tid & 63, og = tid >> 6;
    const float* nb = nin + (size_t)b*128*NS;

    for (int k = tid; k < 24576; k += 512) {
        int j  = k >> 13;
        int c  = (k >> 6) & 127;
        int tt = k & 63;
        int p  = t0 + tt + (j-1)*d;
        pool[k] = ((unsigned)p < NS) ? nb[(size_t)c*NS + p] : 0.f;
    }

    const float4* wg4 = (const float4*)wTl;
    float4 wreg[3];
    #pragma unroll
    for (int i = 0; i < 3; ++i) {
        int idx4 = tid + i*512;
        int sg = idx4/768, j = (idx4/256)%3, rest = idx4%256;
        wreg[i] = wg4[((sg*3+j)*128 + 0)*32 + rest];
    }

    float s[16], g[16];
    #pragma unroll
    for (int i = 0; i < 16; ++i) { int o = og*16+i; s[i] = bs[o]; g[i] = bg[o]; }

    for (int cb = 0; cb < 16; ++cb) {
        int cur = cb & 1;
        float4* wb4 = (float4*)(pool + 24576 + cur*6144);
        #pragma unroll
        for (int i = 0; i < 3; ++i) wb4[tid + i*512] = wreg[i];
        if (cb < 15) {
            int cc0n = (cb+1)*8;
            #pragma unroll
            for (int i = 0; i < 3; ++i) {
                int idx4 = tid + i*512;
                int sg = idx4/768, j = (idx4/256)%3, rest = idx4%256;
                wreg[i] = wg4[((sg*3+j)*128 + cc0n)*32 + rest];
            }
        }
        __syncthreads();
        int cc0 = cb*8;
        const float4* wsb = (const float4*)(pool + 24576 + cur*6144);
        for (int ccx = 0; ccx < 8; ++ccx) {
            int cc = cc0 + ccx;
            float nv0 = pool[        cc*64 + t];
            float nv1 = pool[ 8192 + cc*64 + t];
            float nv2 = pool[16384 + cc*64 + t];
            #pragma unroll
            for (int j = 0; j < 3; ++j) {
                float nv = (j==0) ? nv0 : ((j==1) ? nv1 : nv2);
                const float4* ws4 = wsb + j*256 + ccx*32 + og*4;
                const float4* wgg = ws4 + 768;
                #pragma unroll
                for (int i4 = 0; i4 < 4; ++i4) {
                    float4 a4 = ws4[i4], b4 = wgg[i4];
                    s[i4*4+0] += nv*a4.x; s[i4*4+1] += nv*a4.y;
                    s[i4*4+2] += nv*a4.z; s[i4*4+3] += nv*a4.w;
                    g[i4*4+0] += nv*b4.x; g[i4*4+1] += nv*b4.y;
                    g[i4*4+2] += nv*b4.z; g[i4*4+3] += nv*b4.w;
                }
            }
        }
    }

    float hv[16], sk[16];
    #pragma unroll
    for (int i = 0; i < 16; ++i) {
        hv[i] = tanhf(s[i]) * (1.f/(1.f + __expf(-g[i])));
        sk[i] = pool[8192 + (og*16+i)*64 + t];
    }
    __syncthreads();
    #pragma unroll
    for (int i = 0; i < 16; ++i) pool[(og*16+i)*64 + t] = hv[i];

    float4 wreg2[4];
    #pragma unroll
    for (int i = 0; i < 4; ++i) {
        int idx4 = tid + i*512;
        int arm = idx4 >> 10, rest = idx4 & 1023;
        const float4* src = (const float4*)(arm ? wnTl : woTl);
        wreg2[i] = src[rest];
    }

    float a[16], nn[16];
    #pragma unroll
    for (int i = 0; i < 16; ++i) { a[i] = 0.f; nn[i] = 0.f; }

    for (int cb2 = 0; cb2 < 4; ++cb2) {
        int cur = cb2 & 1;
        float4* w2b = (float4*)(pool + 8192 + cur*8192);
        #pragma unroll
        for (int i = 0; i < 4; ++i) w2b[tid + i*512] = wreg2[i];
        if (cb2 < 3) {
            int cc0n = (cb2+1)*32;
            #pragma unroll
            for (int i = 0; i < 4; ++i) {
                int idx4 = tid + i*512;
                int arm = idx4 >> 10, rest = idx4 & 1023;
                const float4* src = (const float4*)(arm ? wnTl : woTl);
                wreg2[i] = src[cc0n*32 + rest];
            }
        }
        __syncthreads();
        const float4* rb4 = (const float4*)(pool + 8192 + cur*8192);
        for (int cc = 0; cc < 32; ++cc) {
            float hvv = pool[(cb2*32 + cc)*64 + t];
            const float4* wo4 = rb4 + cc*32 + og*4;
            const float4* wn4 = wo4 + 1024;
            #pragma unroll
            for (int i4 = 0; i4 < 4; ++i4) {
                float4 w0 = wo4[i4], w1 = wn4[i4];
                a[i4*4+0]  += hvv*w0.x; a[i4*4+1]  += hvv*w0.y;
                a[i4*4+2]  += hvv*w0.z; a[i4*4+3]  += hvv*w0.w;
                nn[i4*4+0] += hvv*w1.x; nn[i4*4+1] += hvv*w1.y;
                nn[i4*4+2] += hvv*w1.z; nn[i4*4+3] += hvv*w1.w;
            }
        }
    }

    #pragma unroll
    for (int i = 0; i < 16; ++i) {
        int o = og*16 + i;
        size_t gi = (size_t)(b*128 + o)*NS + t0 + t;
        float av = first ? 0.f : acc[gi];
        acc[gi] = av + a[i] + bo[o];
        nout[gi] = nn[i] + bn[o] + sk[i];
    }
}

// ---------------- norms^2 over channels ----------------
__global__ void k_norms(const float* __restrict__ xf, float* __restrict__ norms)
{
    int b = blockIdx.y;
    int t = blockIdx.x*256 + threadIdx.x;
    float a = 0.f;
    for (int c = 0; c < 128; ++c) {
        float v = xf[(size_t)(b*128 + c)*NS + t];
        a += v*v;
    }
    norms[b*NS + t] = a;
}

// ---------------- top-32 per batch (destroys norms) ----------------
__global__ __launch_bounds__(1024) void k_topk(float* __restrict__ norms, float* __restrict__ topv, int* __restrict__ topi)
{
    int b = blockIdx.x;
    int tid = threadIdx.x;
    __shared__ float rv[1024];
    __shared__ int   ri[1024];
    for (int it = 0; it < 32; ++it) {
        float best = -2.f; int bi = 0;
        for (int k = tid; k < NS; k += 1024) {
            float v = norms[b*NS + k];
            if (v > best) { best = v; bi = k; }
        }
        rv[tid] = best; ri[tid] = bi;
        __syncthreads();
        for (int off = 512; off > 0; off >>= 1) {
            if (tid < off) {
                float ov = rv[tid+off]; int oi = ri[tid+off];
                if (ov > rv[tid] || (ov == rv[tid] && oi < ri[tid])) { rv[tid] = ov; ri[tid] = oi; }
            }
            __syncthreads();
        }
        if (tid == 0) {
            topv[b*32 + it] = sqrtf(rv[0]);
            topi[b*32 + it] = ri[0];
            norms[b*NS + ri[0]] = -1.f;
        }
        __syncthreads();
    }
}

// ---------------- gather latents ----------------
__global__ void k_latents(const float* __restrict__ xf, const int* __restrict__ topi, float* __restrict__ lat)
{
    int ev = blockIdx.x; int c = threadIdx.x;
    int b = ev >> 5;
    int idx = topi[ev];
    lat[ev*128 + c] = xf[(size_t)(b*128 + c)*NS + idx];
}

// ---------------- agg = max over time ----------------
__global__ void k_aggmax(const float* __restrict__ xf, float* __restrict__ agg)
{
    int rc = blockIdx.x;
    int tid = threadIdx.x;
    __shared__ float red[256];
    float m = -3.4e38f;
    const float* row = xf + (size_t)rc*NS;
    for (int t = tid; t < NS; t += 256) m = fmaxf(m, row[t]);
    red[tid] = m; __syncthreads();
    for (int off = 128; off > 0; off >>= 1) {
        if (tid < off) red[tid] = fmaxf(red[tid], red[tid+off]);
        __syncthreads();
    }
    if (tid == 0) agg[rc] = red[0];
}

// ---------------- upsample layer for 256 threads: repeat(2)+conv3(pad1)+leaky ----------------
// NPASS o-tiles of OR=128/NPASS outputs; acc per thread = OR/(256/L2) <= 16.
template<int L2, int NPASS>
__device__ __forceinline__ void up_layerS(const float* __restrict__ wbase, const float* __restrict__ bias,
                                          const float* __restrict__ inb, float* __restrict__ outb,
                                          float* __restrict__ wst, int tid)
{
    constexpr int Lin = L2/2;
    constexpr int OGC = 256/L2;
    constexpr int OR  = 128/NPASS;
    constexpr int NO  = OR/OGC;
    constexpr int LOG = (L2==16)?4:(L2==32)?5:(L2==64)?6:7;
    int p  = tid & (L2-1);
    int og = tid >> LOG;
    int o0 = og*NO;
    for (int pass = 0; pass < NPASS; ++pass) {
        int obase = pass*OR;
        float acc[NO];
        #pragma unroll
        for (int k = 0; k < NO; ++k) acc[k] = 0.f;
        for (int cc0 = 0; cc0 < 128; cc0 += 16) {
            __syncthreads();
            for (int k = tid; k < 16*3*OR; k += 256) {
                int ci = k / (3*OR); int rem = k - ci*(3*OR);
                int j = rem / OR; int oo = rem - j*OR;
                wst[k] = wbase[(cc0+ci)*384 + j*128 + obase + oo];
            }
            __syncthreads();
            for (int ci = 0; ci < 16; ++ci) {
                int c = cc0 + ci;
                float xv[3];
                #pragma unroll
                for (int j = 0; j < 3; ++j) {
                    int iu = p + j - 1;
                    xv[j] = ((unsigned)iu < (unsigned)L2) ? inb[c*Lin + (iu>>1)] : 0.f;
                }
                #pragma unroll
                for (int j = 0; j < 3; ++j) {
                    const float4* w4 = (const float4*)(wst + ci*3*OR + j*OR + o0);
                    #pragma unroll
                    for (int q = 0; q < NO/4; ++q) {
                        float4 w = w4[q];
                        acc[q*4+0] += xv[j]*w.x; acc[q*4+1] += xv[j]*w.y;
                        acc[q*4+2] += xv[j]*w.z; acc[q*4+3] += xv[j]*w.w;
                    }
                }
            }
        }
        #pragma unroll
        for (int k = 0; k < NO; ++k)
            outb[(obase + o0 + k)*L2 + p] = leakyf(acc[k] + bias[obase + o0 + k]);
    }
}

// ---------------- fused conv_up: gridDim=(128 events, 2 modes), 256 threads ----------------
// 256-thread blocks get the full 256-VGPR budget (r2's kernel measured 132 without a cap);
// every phase keeps <=16 accumulators/thread so nothing spills.
__global__ void k_convup3(const float* __restrict__ lat,
    const float* __restrict__ elw, const float* __restrict__ elb, const float* __restrict__ ecb,
    const float* __restrict__ efw, const float* __restrict__ efb,
    const float* __restrict__ tlw, const float* __restrict__ tlb, const float* __restrict__ tcb,
    const float* __restrict__ tfb, const float* __restrict__ wtu, const float* __restrict__ wtf,
    float* __restrict__ envsq, float* __restrict__ tfT)
{
    __shared__ float pool[35008]; // 136.75 KB
    float* latv = pool;           // 128
    float* bufA = pool + 128;     // 4160: layers <=32-wide; later trb[32][129]=4128
    float* bufB = pool + 4288;    // 8192: 16- and 64-wide stages
    float* bufC = pool + 12480;   // 16384: [128][128]
    float* wst  = pool + 28864;   // 6144
    int ev = blockIdx.x;
    int m  = blockIdx.y;
    int tid = threadIdx.x;
    const float* lw = m ? tlw : elw;
    const float* lb = m ? tlb : elb;
    const float* cb = m ? tcb : ecb;
    const float* wu = wtu + m*4*49152;
    if (tid < 128) latv[tid] = lat[ev*128 + tid];
    __syncthreads();
    for (int jj = tid; jj < 1024; jj += 256) {
        float a = lb[jj];
        const float4* w4 = (const float4*)(lw + jj*128);
        #pragma unroll 8
        for (int q = 0; q < 32; ++q) {
            float4 w = w4[q];
            a += w.x*latv[q*4] + w.y*latv[q*4+1] + w.z*latv[q*4+2] + w.w*latv[q*4+3];
        }
        bufA[(jj>>3)*8 + (jj&7)] = a;
    }
    up_layerS<16,1>(wu,        cb,     bufA, bufB, wst, tid);   // [128][8] -> [128][16]
    up_layerS<32,1>(wu+49152,  cb+128, bufB, bufA, wst, tid);   // -> [128][32]
    up_layerS<64,2>(wu+98304,  cb+256, bufA, bufB, wst, tid);   // -> [128][64]
    up_layerS<128,4>(wu+147456,cb+384, bufB, bufC, wst, tid);   // -> [128][128]
    __syncthreads();
    int p = tid & 127, g = tid >> 7;  // g in 0..1
    if (m == 0) {
        float s = 0.f;
        for (int c = g*64; c < g*64+64; ++c) {
            #pragma unroll
            for (int j = 0; j < 3; ++j) {
                int iu = p + j - 1;
                float xv = ((unsigned)iu < 128u) ? bufC[c*128 + iu] : 0.f;
                s += efw[c*3+j]*xv;
            }
        }
        wst[g*128 + p] = s;
        __syncthreads();
        if (g == 0) {
            float a = wst[p] + wst[128+p] + efb[0];
            envsq[ev*128 + p] = a*a;
        }
    } else {
        float* trb = bufA;   // [32ct][stride 129]
        for (int ctb = 0; ctb < 17; ++ctb) {
            int ct0 = ctb*32;
            float acc[16];
            #pragma unroll
            for (int i = 0; i < 16; ++i) acc[i] = 0.f;
            for (int cc0 = 0; cc0 < 128; cc0 += 16) {
                __syncthreads();
                for (int k = tid; k < 1536; k += 256) {
                    int ci = k / 96, rem = k - ci*96;
                    int j = rem >> 5, ctl = rem & 31;
                    wst[k] = wtf[(cc0+ci)*1632 + j*544 + ct0 + ctl];
                }
                __syncthreads();
                for (int ci = 0; ci < 16; ++ci) {
                    int c = cc0 + ci;
                    float xv[3];
                    #pragma unroll
                    for (int j = 0; j < 3; ++j) {
                        int iu = p + j - 1;
                        xv[j] = ((unsigned)iu < 128u) ? bufC[c*128 + iu] : 0.f;
                    }
                    #pragma unroll
                    for (int j = 0; j < 3; ++j) {
                        const float4* w4 = (const float4*)(wst + ci*96 + j*32 + g*16);
                        #pragma unroll
                        for (int q = 0; q < 4; ++q) {
                            float4 w = w4[q];
                            acc[q*4+0] += xv[j]*w.x; acc[q*4+1] += xv[j]*w.y;
                            acc[q*4+2] += xv[j]*w.z; acc[q*4+3] += xv[j]*w.w;
                        }
                    }
                }
            }
            __syncthreads();      // prior trb readers done (stage/compute syncs above also fence)
            #pragma unroll
            for (int i = 0; i < 16; ++i) trb[(g*16 + i)*129 + p] = acc[i];
            __syncthreads();
            int ctl2 = tid & 31, pg = tid >> 5;   // 8 p-groups
            #pragma unroll
            for (int ps = 0; ps < 16; ++ps) {
                int pp = ps*8 + pg;
                int ct = ct0 + ctl2;
                if (ct < 514)
                    tfT[(size_t)(ev*128 + pp)*514 + ct] = trb[ctl2*129 + pp] + tfb[ct];
            }
            __syncthreads();
        }
    }
}

// ---------------- impulse transfer lin_stack ----------------
__global__ __launch_bounds__(128) void k_itf(const float* __restrict__ lat,
    const float* __restrict__ iw, const float* __restrict__ ib,
    const float* __restrict__ iow, const float* __restrict__ iob,
    float* __restrict__ itf)
{
    int ev = blockIdx.x; int tid = threadIdx.x;
    __shared__ float xa[128], xb[128];
    xa[tid] = lat[ev*128 + tid];
    __syncthreads();
    float* src = xa; float* dst = xb;
    for (int l = 0; l < 3; ++l) {
        float a = ib[l*128 + tid];
        const float* wr = iw + (l*128 + tid)*128;
        for (int k = 0; k < 128; ++k) a += wr[k]*src[k];
        dst[tid] = leakyf(a);
        __syncthreads();
        float* tmp = src; src = dst; dst = tmp;
    }
    for (int o = tid; o < 514; o += 128) {
        float a = iob[o];
        const float* wr = iow + o*128;
        for (int k = 0; k < 128; ++k) a += wr[k]*src[k];
        itf[ev*514 + o] = a;
    }
}

// ---------------- room/mix lin_stacks + softmax ----------------
__global__ __launch_bounds__(128) void k_roommix(const float* __restrict__ agg,
    const float* __restrict__ rw, const float* __restrict__ rb,
    const float* __restrict__ row_, const float* __restrict__ rob,
    const float* __restrict__ mw, const float* __restrict__ mb,
    const float* __restrict__ mow, const float* __restrict__ mob,
    float* __restrict__ probs, float* __restrict__ mval)
{
    int b = blockIdx.x; int tid = threadIdx.x;
    __shared__ float xa[128], xb[128], rr[8];
    xa[tid] = agg[b*128 + tid];
    __syncthreads();
    float* src = xa; float* dst = xb;
    for (int l = 0; l < 3; ++l) {
        float a = rb[l*128 + tid];
        const float* wr = rw + (l*128 + tid)*128;
        for (int k = 0; k < 128; ++k) a += wr[k]*src[k];
        dst[tid] = leakyf(a);
        __syncthreads();
        float* tmp = src; src = dst; dst = tmp;
    }
    if (tid < 8) {
        float a = rob[tid];
        const float* wr = row_ + tid*128;
        for (int k = 0; k < 128; ++k) a += wr[k]*src[k];
        rr[tid] = a;
    }
    __syncthreads();
    if (tid == 0) {
        float m = rr[0];
        for (int j = 1; j < 8; ++j) m = fmaxf(m, rr[j]);
        float ssum = 0.f; float e[8];
        for (int j = 0; j < 8; ++j) { e[j] = __expf(rr[j]-m); ssum += e[j]; }
        for (int j = 0; j < 8; ++j) probs[b*8+j] = e[j]/ssum;
    }
    __syncthreads();
    xa[tid] = agg[b*128 + tid];
    __syncthreads();
    src = xa; dst = xb;
    for (int l = 0; l < 3; ++l) {
        float a = mb[l*128 + tid];
        const float* wr = mw + (l*128 + tid)*128;
        for (int k = 0; k < 128; ++k) a += wr[k]*src[k];
        dst[tid] = leakyf(a);
        __syncthreads();
        float* tmp = src; src = dst; dst = tmp;
    }
    if (tid == 0) {
        float a = mob[0];
        for (int k = 0; k < 128; ++k) a += mow[k]*src[k];
        mval[b] = a;
    }
}

// ---------------- ir = softmax(r) @ rooms ----------------
__global__ void k_ir(const float* __restrict__ probs, const float* __restrict__ rooms, float* __restrict__ ir)
{
    int b = blockIdx.y;
    int t = blockIdx.x*256 + threadIdx.x;
    float a = 0.f;
    for (int j = 0; j < 8; ++j) a += probs[b*8+j]*rooms[j*NS + t];
    ir[b*NS + t] = a;
}

// ---------------- 512-pt complex FFT in LDS (256 threads) ----------------
__device__ __forceinline__ void fft512(float* re, float* im, const float* twr, const float* twi, int tid, bool inverse)
{
    for (int w = tid; w < 512; w += 256) {
        unsigned r = __brev((unsigned)w) >> 23;
        if ((int)r > w) {
            float tr = re[w]; re[w] = re[r]; re[r] = tr;
            float ti = im[w]; im[w] = im[r]; im[r] = ti;
        }
    }
    __syncthreads();
    for (int s = 0; s < 9; ++s) {
        int half = 1 << s;
        int grp = tid >> s;
        int pos = tid & (half-1);
        int i0 = (grp << (s+1)) + pos;
        int i1 = i0 + half;
        int twidx = pos << (8 - s);
        float wr = twr[twidx];
        float wi = inverse ? -twi[twidx] : twi[twidx];
        float r1 = re[i1], q1 = im[i1];
        float tr = wr*r1 - wi*q1;
        float ti = wr*q1 + wi*r1;
        float r0 = re[i0], q0 = im[i0];
        re[i1] = r0 - tr; im[i1] = q0 - ti;
        re[i0] = r0 + tr; im[i0] = q0 + ti;
        __syncthreads();
    }
}

// ---------------- per-event scan: impulse -> 128 frames of env*imp + carry -> FFT filter -> OLA ----------------
__global__ __launch_bounds__(256) void k_event(const float* __restrict__ tfT, const float* __restrict__ itf,
    const float* __restrict__ envsq, const float* __restrict__ noise, float* __restrict__ atoms)
{
    int ev = blockIdx.x; int tid = threadIdx.x;
    __shared__ float twr[256], twi[256];
    __shared__ float re[512], im[512], carry[512], imp[512], ham[512], acc[256], envl[128];
    if (tid < 128) envl[tid] = envsq[ev*128 + tid];
    {
        float ang = -6.283185307179586f * (float)tid / 512.0f;
        float si, co;
        sincosf(ang, &si, &co);
        twr[tid] = co; twi[tid] = si;
    }
    for (int w = tid; w < 512; w += 256) {
        ham[w] = 0.54f - 0.46f*cosf(6.283185307179586f * (float)w / 512.0f);
        re[w] = noise[w]; im[w] = 0.f; carry[w] = 0.f;
    }
    acc[tid] = 0.f;
    __syncthreads();
    fft512(re, im, twr, twi, tid, false);
    {
        const float* tp = itf + ev*514;
        int k = tid;
        float xr = re[k], xi = im[k];
        float tr = tp[2*k], ti = tp[2*k+1];
        float sr = xr*tr - xi*ti;
        float si = xr*ti + xi*tr;
        if (k == 0) si = 0.f;
        re[k] = sr; im[k] = si;
        if (k >= 1) { re[512-k] = sr; im[512-k] = -si; }
        if (tid == 0) {
            float xr2 = re[256], xi2 = im[256];
            float sr2 = xr2*tp[512] - xi2*tp[513];
            re[256] = sr2; im[256] = 0.f;
        }
    }
    __syncthreads();
    fft512(re, im, twr, twi, tid, true);
    for (int w = tid; w < 512; w += 256) imp[w] = re[w] * (1.0f/512.0f);
    __syncthreads();
    const float inv512 = 1.0f/512.0f;
    for (int f = 0; f < 128; ++f) {
        for (int w = tid; w < 512; w += 256) {
            int tg = f*256 + w;
            float e = 0.f;
            if (tg < NS) {
                float srcp = ((float)tg + 0.5f)*(1.0f/256.0f) - 0.5f;
                srcp = fminf(fmaxf(srcp, 0.f), 127.f);
                int i0 = (int)srcp;
                float fr = srcp - (float)i0;
                int i1 = i0 + 1; if (i1 > 127) i1 = 127;
                e = envl[i0]*(1.f-fr) + envl[i1]*fr;
            }
            re[w] = imp[w]*e + carry[w];
            im[w] = 0.f;
        }
        __syncthreads();
        fft512(re, im, twr, twi, tid, false);
        {
            const float* tp = tfT + ((size_t)ev*128 + f)*514;
            int k = tid;
            float xr = re[k], xi = im[k];
            float tr = tp[2*k], ti = tp[2*k+1];
            float sr = xr*tr - xi*ti;
            float si = xr*ti + xi*tr;
            if (k == 0) si = 0.f;
            re[k] = sr; im[k] = si;
            if (k >= 1) { re[512-k] = sr; im[512-k] = -si; }
            if (tid == 0) {
                float xr2 = re[256], xi2 = im[256];
                float sr2 = xr2*tp[512] - xi2*tp[513];
                re[256] = sr2; im[256] = 0.f;
            }
        }
        __syncthreads();
        fft512(re, im, twr, twi, tid, true);
        float o0 = re[tid]     * inv512 * ham[tid];
        float o1 = re[tid+256] * inv512 * ham[tid+256];
        atoms[(size_t)ev*NS + f*256 + tid] = o0 + acc[tid];
        acc[tid] = o1;
        carry[tid] = o0;
        carry[tid+256] = o1;
        __syncthreads();
    }
}

// ---------------- final = sum_a values[a]*atoms[a, t-idx[a]] ----------------
__global__ void k_gather(const float* __restrict__ atoms, const float* __restrict__ topv,
                         const int* __restrict__ topi, float* __restrict__ fin)
{
    int b = blockIdx.y;
    int t = blockIdx.x*256 + threadIdx.x;
    float s = 0.f;
    for (int a = 0; a < 32; ++a) {
        int ii = topi[b*32 + a];
        if (ii <= t) s += topv[b*32 + a] * atoms[(size_t)(b*32 + a)*NS + (t - ii)];
    }
    fin[b*NS + t] = s;
}

// ---------------- wet = final (*) ir (causal direct conv), out = m*wet + final*(1-m) ----------------
__global__ __launch_bounds__(256) void k_wet(const float* __restrict__ fin, const float* __restrict__ ir,
    const float* __restrict__ mval, float* __restrict__ out)
{
    int b = blockIdx.y;
    int t0 = blockIdx.x*256;
    int tid = threadIdx.x;
    __shared__ float fs[256];
    __shared__ float irw[512];
    float wet = 0.f;
    for (int c0 = 0; c0 <= t0; c0 += 256) {
        __syncthreads();
        fs[tid] = fin[b*NS + c0 + tid];
        int dmin = t0 - c0 - 255;
        for (int q = tid; q < 511; q += 256) {
            int dd = dmin + q;
            irw[q] = ((unsigned)dd < NS) ? ir[b*NS + dd] : 0.f;
        }
        __syncthreads();
        if (c0 < t0) {
            #pragma unroll 8
            for (int k = 0; k < 256; ++k) wet += fs[k]*irw[tid + 255 - k];
        } else {
            for (int k = 0; k <= tid; ++k) wet += fs[k]*irw[tid + 255 - k];
        }
    }
    float m = mval[b];
    float fv = fin[b*NS + t0 + tid];
    out[b*NS + t0 + tid] = m*wet + fv*(1.f - m);
}

extern "C" void kernel_launch(void* const* d_in, const int* in_sizes, int n_in,
                              void* d_out, int out_size, void* d_ws, size_t ws_size,
                              hipStream_t stream)
{
    (void)in_sizes; (void)n_in; (void)out_size; (void)ws_size;
    const float* x    = (const float*)d_in[0];
    const float* fbw  = (const float*)d_in[1];
    const float* dsw  = (const float*)d_in[2];
    const float* dsb  = (const float*)d_in[3];
    const float* dgw  = (const float*)d_in[4];
    const float* dgb  = (const float*)d_in[5];
    const float* dow  = (const float*)d_in[6];
    const float* dob  = (const float*)d_in[7];
    const float* dnw  = (const float*)d_in[8];
    const float* dnb  = (const float*)d_in[9];
    const float* elw  = (const float*)d_in[10];
    const float* elb  = (const float*)d_in[11];
    const float* ecw  = (const float*)d_in[12];
    const float* ecb  = (const float*)d_in[13];
    const float* efw  = (const float*)d_in[14];
    const float* efb  = (const float*)d_in[15];
    const float* tlw  = (const float*)d_in[16];
    const float* tlb  = (const float*)d_in[17];
    const float* tcw  = (const float*)d_in[18];
    const float* tcb  = (const float*)d_in[19];
    const float* tfw  = (const float*)d_in[20];
    const float* tfb  = (const float*)d_in[21];
    const float* iw   = (const float*)d_in[22];
    const float* ib   = (const float*)d_in[23];
    const float* iow  = (const float*)d_in[24];
    const float* iob  = (const float*)d_in[25];
    const float* rw   = (const float*)d_in[26];
    const float* rb   = (const float*)d_in[27];
    const float* row_ = (const float*)d_in[28];
    const float* rob  = (const float*)d_in[29];
    const float* mw   = (const float*)d_in[30];
    const float* mb   = (const float*)d_in[31];
    const float* mow  = (const float*)d_in[32];
    const float* mob  = (const float*)d_in[33];
    const float* rooms= (const float*)d_in[34];
    const float* noise= (const float*)d_in[35];

    float* ws   = (float*)d_ws;
    float* n0   = ws;                       // 16,777,216
    float* n1   = ws + 16777216;            // 16,777,216
    float* accb = ws + 33554432;            // 16,777,216
    float* wT   = ws + 50331648;            // 1,376,256
    float* woT  = ws + 51707904;            // 114,688
    float* wnT  = ws + 51822592;            // 114,688
    float* envsq= ws + 51937280;            // 16,384
    float* lat  = ws + 51953664;            // 16,384
    float* itfb = ws + 51970048;            // 65,792
    float* norms= ws + 52035840;            // 131,072
    float* topv = ws + 52166912;            // 128
    int*   topi = (int*)(ws + 52167040);    // 128
    float* agg  = ws + 52167168;            // 512
    float* probs= ws + 52167680;            // 32
    float* mval = ws + 52167712;            // 32
    float* irb  = ws + 52167744;            // 131,072
    float* fin  = ws + 52298816;            // 131,072
    float* tfT  = n0;                        // reuse after dilated stack is done
    float* atoms= n0 + 8421376;              // reuse (8.42M + 4.19M < 16.77M)
    float* wtu  = n1;                        // 393,216  (n1 free after stack)
    float* wtf  = n1 + 393216;               // 208,896

    float* out = (float*)d_out;

    k_wtrans<<<dim3((1376256+255)/256), dim3(256), 0, stream>>>(dsw, dgw, wT);
    k_wtrans2<<<dim3((114688+255)/256), dim3(256), 0, stream>>>(dow, dnw, woT, wnT);
    k_front<<<dim3(512,4), dim3(512), 0, stream>>>(x, fbw, n0);

    const int dil[7] = {1,3,9,27,81,243,1};
    float* cin = n0; float* cout = n1;
    for (int l = 0; l < 7; ++l) {
        k_layer<<<dim3(512,4), dim3(512), 0, stream>>>(
            cin, cout, accb, wT + l*98304,
            dsb + l*128, dgb + l*128,
            woT + l*16384, dob + l*128,
            wnT + l*16384, dnb + l*128,
            dil[l], l==0 ? 1 : 0);
        float* tmp = cin; cin = cout; cout = tmp;
    }
    k_norms<<<dim3(128,4), dim3(256), 0, stream>>>(accb, norms);
    k_topk<<<dim3(4), dim3(1024), 0, stream>>>(norms, topv, topi);
    k_latents<<<dim3(128), dim3(128), 0, stream>>>(accb, topi, lat);
    k_aggmax<<<dim3(512), dim3(256), 0, stream>>>(accb, agg);
    // n1 is dead after the stack (final n unused by the reference) -> carve conv_up weights from it
    k_wtrans_up<<<dim3(1536), dim3(256), 0, stream>>>(ecw, tcw, tfw, wtu, wtf);
    k_convup3<<<dim3(128,2), dim3(256), 0, stream>>>(lat, elw, elb, ecb, efw, efb,
                                                     tlw, tlb, tcb, tfb, wtu, wtf, envsq, tfT);
    k_itf<<<dim3(128), dim3(128), 0, stream>>>(lat, iw, ib, iow, iob, itfb);
    k_roommix<<<dim3(4), dim3(128), 0, stream>>>(agg, rw, rb, row_, rob, mw, mb, mow, mob, probs, mval);
    k_ir<<<dim3(128,4), dim3(256), 0, stream>>>(probs, rooms, irb);
    k_event<<<dim3(128), dim3(256), 0, stream>>>(tfT, itfb, envsq, noise, atoms);
    k_gather<<<dim3(128,4), dim3(256), 0, stream>>>(atoms, topv, topi, fin);
    k_wet<<<dim3(128,4), dim3(256), 0, stream>>>(fin, irb, mval, out);
}

// Round 9
// 9584.362 us; speedup vs baseline: 9.3901x; 1.1234x over previous
//
#include <hip/hip_runtime.h>
#include <math.h>

#define NS 32768

static __device__ __forceinline__ float leakyf(float x){ return x >= 0.f ? x : 0.2f*x; }

// ---------------- weight transpose for dilated stack: wT[l][sg][j][cc][o] ----------------
__global__ void k_wtrans(const float* __restrict__ ws, const float* __restrict__ wg, float* __restrict__ wT)
{
    int idx = blockIdx.x*256 + threadIdx.x;
    const int total = 7*2*3*128*128;
    if (idx >= total) return;
    int o  = idx & 127;
    int cc = (idx >> 7) & 127;
    int j  = (idx >> 14) % 3;
    int sg = (idx / 49152) & 1;
    int l  = idx / 98304;
    const float* src = sg ? wg : ws;
    wT[idx] = src[((l*128 + o)*128 + cc)*3 + j];
}

// ---------------- stage-2 weight transpose: woT/wnT [l][c][o] ----------------
__global__ void k_wtrans2(const float* __restrict__ wo, const float* __restrict__ wn,
                          float* __restrict__ woT, float* __restrict__ wnT)
{
    int idx = blockIdx.x*256 + threadIdx.x;
    if (idx >= 7*128*128) return;
    int o = idx & 127;
    int c = (idx >> 7) & 127;
    int l = idx >> 14;
    woT[idx] = wo[(l*128 + o)*128 + c];
    wnT[idx] = wn[(l*128 + o)*128 + c];
}

// ---------------- conv_up weight transposes ----------------
// wtu[(mode*4+layer)][c][j][o=128]   (8*128*3*128 = 393216)
// wtf[c][j][ctp=544 (zero-padded)]   (128*3*544   = 208896)
__global__ void k_wtrans_up(const float* __restrict__ ecw, const float* __restrict__ tcw,
                            const float* __restrict__ tfw, float* __restrict__ wtu, float* __restrict__ wtf)
{
    int idx = blockIdx.x*256 + threadIdx.x;
    if (idx < 393216) {
        int o = idx & 127;
        int j = (idx >> 7) % 3;
        int c = (idx / 384) & 127;
        int ml = idx / 49152;
        const float* src = (ml < 4 ? ecw : tcw) + (ml & 3)*49152;
        wtu[idx] = src[(o*128 + c)*3 + j];
    }
    if (idx < 208896) {
        int ct = idx % 544;
        int j = (idx / 544) % 3;
        int c = idx / 1632;
        wtf[idx] = (ct < 514) ? tfw[(ct*128 + c)*3 + j] : 0.f;
    }
}

// ---------------- front conv: n[b,c,t] = sum_k x[b, t+k-256] * fbw[c,k] ----------------
__global__ __launch_bounds__(512) void k_front(const float* __restrict__ x, const float* __restrict__ fbw,
                                               float* __restrict__ n0)
{
    int b = blockIdx.y;
    int t0 = blockIdx.x * 64;
    int tid = threadIdx.x;
    int t = tid & 63, og = tid >> 6;
    __shared__ float xs[576];
    __shared__ float4 wl[2048]; // [c][k4] 64 k per chunk
    for (int i = tid; i < 575; i += 512) {
        int p = t0 + i - 256;
        xs[i] = ((unsigned)p < NS) ? x[b*NS + p] : 0.f;
    }
    float s[16];
    #pragma unroll
    for (int i = 0; i < 16; ++i) s[i] = 0.f;
    for (int kc = 0; kc < 8; ++kc) {
        __syncthreads();
        for (int i = tid; i < 2048; i += 512) {
            int c = i >> 4, k4 = i & 15;
            wl[i] = *(const float4*)(fbw + c*512 + kc*64 + k4*4);
        }
        __syncthreads();
        for (int k4 = 0; k4 < 16; ++k4) {
            int base = t + kc*64 + k4*4;
            float xv0 = xs[base+0], xv1 = xs[base+1], xv2 = xs[base+2], xv3 = xs[base+3];
            #pragma unroll
            for (int i = 0; i < 16; ++i) {
                float4 w = wl[(og*16 + i)*16 + k4];
                s[i] += w.x*xv0 + w.y*xv1 + w.z*xv2 + w.w*xv3;
            }
        }
    }
    #pragma unroll
    for (int i = 0; i < 16; ++i)
        n0[(size_t)(b*128 + og*16 + i)*NS + t0 + t] = s[i];
}

// ---------------- one dilated gated layer (LDS-staged, double-buffered weights) ----------------
__global__ __launch_bounds__(512) void k_layer(const float* __restrict__ nin, float* __restrict__ nout,
        float* __restrict__ acc, const float* __restrict__ wTl,
        const float* __restrict__ bs, const float* __restrict__ bg,
        const float* __restrict__ woTl, const float* __restrict__ bo,
        const float* __restrict__ wnTl, const float* __restrict__ bn,
        int d, int first)
{
    __shared__ float pool[36864]; // 144 KB
    int b = blockIdx.y;
    int t0 = blockIdx.x * 64;
    int tid = threadIdx.x;
    int t = tid & 63, og = tid >> 6;
    const float* nb = nin + (size_t)b*128*NS;

    for (int k = tid; k < 24576; k += 512) {
        int j  = k >> 13;
        int c  = (k >> 6) & 127;
        int tt = k & 63;
        int p  = t0 + tt + (j-1)*d;
        pool[k] = ((unsigned)p < NS) ? nb[(size_t)c*NS + p] : 0.f;
    }

    const float4* wg4 = (const float4*)wTl;
    float4 wreg[3];
    #pragma unroll
    for (int i = 0; i < 3; ++i) {
        int idx4 = tid + i*512;
        int sg = idx4/768, j = (idx4/256)%3, rest = idx4%256;
        wreg[i] = wg4[((sg*3+j)*128 + 0)*32 + rest];
    }

    float s[16], g[16];
    #pragma unroll
    for (int i = 0; i < 16; ++i) { int o = og*16+i; s[i] = bs[o]; g[i] = bg[o]; }

    for (int cb = 0; cb < 16; ++cb) {
        int cur = cb & 1;
        float4* wb4 = (float4*)(pool + 24576 + cur*6144);
        #pragma unroll
        for (int i = 0; i < 3; ++i) wb4[tid + i*512] = wreg[i];
        if (cb < 15) {
            int cc0n = (cb+1)*8;
            #pragma unroll
            for (int i = 0; i < 3; ++i) {
                int idx4 = tid + i*512;
                int sg = idx4/768, j = (idx4/256)%3, rest = idx4%256;
                wreg[i] = wg4[((sg*3+j)*128 + cc0n)*32 + rest];
            }
        }
        __syncthreads();
        int cc0 = cb*8;
        const float4* wsb = (const float4*)(pool + 24576 + cur*6144);
        for (int ccx = 0; ccx < 8; ++ccx) {
            int cc = cc0 + ccx;
            float nv0 = pool[        cc*64 + t];
            float nv1 = pool[ 8192 + cc*64 + t];
            float nv2 = pool[16384 + cc*64 + t];
            #pragma unroll
            for (int j = 0; j < 3; ++j) {
                float nv = (j==0) ? nv0 : ((j==1) ? nv1 : nv2);
                const float4* ws4 = wsb + j*256 + ccx*32 + og*4;
                const float4* wgg = ws4 + 768;
                #pragma unroll
                for (int i4 = 0; i4 < 4; ++i4) {
                    float4 a4 = ws4[i4], b4 = wgg[i4];
                    s[i4*4+0] += nv*a4.x; s[i4*4+1] += nv*a4.y;
                    s[i4*4+2] += nv*a4.z; s[i4*4+3] += nv*a4.w;
                    g[i4*4+0] += nv*b4.x; g[i4*4+1] += nv*b4.y;
                    g[i4*4+2] += nv*b4.z; g[i4*4+3] += nv*b4.w;
                }
            }
        }
    }

    float hv[16], sk[16];
    #pragma unroll
    for (int i = 0; i < 16; ++i) {
        hv[i] = tanhf(s[i]) * (1.f/(1.f + __expf(-g[i])));
        sk[i] = pool[8192 + (og*16+i)*64 + t];
    }
    __syncthreads();
    #pragma unroll
    for (int i = 0; i < 16; ++i) pool[(og*16+i)*64 + t] = hv[i];

    float4 wreg2[4];
    #pragma unroll
    for (int i = 0; i < 4; ++i) {
        int idx4 = tid + i*512;
        int arm = idx4 >> 10, rest = idx4 & 1023;
        const float4* src = (const float4*)(arm ? wnTl : woTl);
        wreg2[i] = src[rest];
    }

    float a[16], nn[16];
    #pragma unroll
    for (int i = 0; i < 16; ++i) { a[i] = 0.f; nn[i] = 0.f; }

    for (int cb2 = 0; cb2 < 4; ++cb2) {
        int cur = cb2 & 1;
        float4* w2b = (float4*)(pool + 8192 + cur*8192);
        #pragma unroll
        for (int i = 0; i < 4; ++i) w2b[tid + i*512] = wreg2[i];
        if (cb2 < 3) {
            int cc0n = (cb2+1)*32;
            #pragma unroll
            for (int i = 0; i < 4; ++i) {
                int idx4 = tid + i*512;
                int arm = idx4 >> 10, rest = idx4 & 1023;
                const float4* src = (const float4*)(arm ? wnTl : woTl);
                wreg2[i] = src[cc0n*32 + rest];
            }
        }
        __syncthreads();
        const float4* rb4 = (const float4*)(pool + 8192 + cur*8192);
        for (int cc = 0; cc < 32; ++cc) {
            float hvv = pool[(cb2*32 + cc)*64 + t];
            const float4* wo4 = rb4 + cc*32 + og*4;
            const float4* wn4 = wo4 + 1024;
            #pragma unroll
            for (int i4 = 0; i4 < 4; ++i4) {
                float4 w0 = wo4[i4], w1 = wn4[i4];
                a[i4*4+0]  += hvv*w0.x; a[i4*4+1]  += hvv*w0.y;
                a[i4*4+2]  += hvv*w0.z; a[i4*4+3]  += hvv*w0.w;
                nn[i4*4+0] += hvv*w1.x; nn[i4*4+1] += hvv*w1.y;
                nn[i4*4+2] += hvv*w1.z; nn[i4*4+3] += hvv*w1.w;
            }
        }
    }

    #pragma unroll
    for (int i = 0; i < 16; ++i) {
        int o = og*16 + i;
        size_t gi = (size_t)(b*128 + o)*NS + t0 + t;
        float av = first ? 0.f : acc[gi];
        acc[gi] = av + a[i] + bo[o];
        nout[gi] = nn[i] + bn[o] + sk[i];
    }
}

// ---------------- norms^2 over channels ----------------
__global__ void k_norms(const float* __restrict__ xf, float* __restrict__ norms)
{
    int b = blockIdx.y;
    int t = blockIdx.x*256 + threadIdx.x;
    float a = 0.f;
    for (int c = 0; c < 128; ++c) {
        float v = xf[(size_t)(b*128 + c)*NS + t];
        a += v*v;
    }
    norms[b*NS + t] = a;
}

// ---------------- top-32 per batch (destroys norms) ----------------
__global__ __launch_bounds__(1024) void k_topk(float* __restrict__ norms, float* __restrict__ topv, int* __restrict__ topi)
{
    int b = blockIdx.x;
    int tid = threadIdx.x;
    __shared__ float rv[1024];
    __shared__ int   ri[1024];
    for (int it = 0; it < 32; ++it) {
        float best = -2.f; int bi = 0;
        for (int k = tid; k < NS; k += 1024) {
            float v = norms[b*NS + k];
            if (v > best) { best = v; bi = k; }
        }
        rv[tid] = best; ri[tid] = bi;
        __syncthreads();
        for (int off = 512; off > 0; off >>= 1) {
            if (tid < off) {
                float ov = rv[tid+off]; int oi = ri[tid+off];
                if (ov > rv[tid] || (ov == rv[tid] && oi < ri[tid])) { rv[tid] = ov; ri[tid] = oi; }
            }
            __syncthreads();
        }
        if (tid == 0) {
            topv[b*32 + it] = sqrtf(rv[0]);
            topi[b*32 + it] = ri[0];
            norms[b*NS + ri[0]] = -1.f;
        }
        __syncthreads();
    }
}

// ---------------- gather latents ----------------
__global__ void k_latents(const float* __restrict__ xf, const int* __restrict__ topi, float* __restrict__ lat)
{
    int ev = blockIdx.x; int c = threadIdx.x;
    int b = ev >> 5;
    int idx = topi[ev];
    lat[ev*128 + c] = xf[(size_t)(b*128 + c)*NS + idx];
}

// ---------------- agg = max over time ----------------
__global__ void k_aggmax(const float* __restrict__ xf, float* __restrict__ agg)
{
    int rc = blockIdx.x;
    int tid = threadIdx.x;
    __shared__ float red[256];
    float m = -3.4e38f;
    const float* row = xf + (size_t)rc*NS;
    for (int t = tid; t < NS; t += 256) m = fmaxf(m, row[t]);
    red[tid] = m; __syncthreads();
    for (int off = 128; off > 0; off >>= 1) {
        if (tid < off) red[tid] = fmaxf(red[tid], red[tid+off]);
        __syncthreads();
    }
    if (tid == 0) agg[rc] = red[0];
}

// ---------------- upsample layer for 256 threads: repeat(2)+conv3(pad1)+leaky ----------------
// NPASS o-tiles of OR=128/NPASS outputs; acc per thread = OR/(256/L2) <= 16.
template<int L2, int NPASS>
__device__ __forceinline__ void up_layerS(const float* __restrict__ wbase, const float* __restrict__ bias,
                                          const float* __restrict__ inb, float* __restrict__ outb,
                                          float* __restrict__ wst, int tid)
{
    constexpr int Lin = L2/2;
    constexpr int OGC = 256/L2;
    constexpr int OR  = 128/NPASS;
    constexpr int NO  = OR/OGC;
    constexpr int LOG = (L2==16)?4:(L2==32)?5:(L2==64)?6:7;
    int p  = tid & (L2-1);
    int og = tid >> LOG;
    int o0 = og*NO;
    for (int pass = 0; pass < NPASS; ++pass) {
        int obase = pass*OR;
        float acc[NO];
        #pragma unroll
        for (int k = 0; k < NO; ++k) acc[k] = 0.f;
        for (int cc0 = 0; cc0 < 128; cc0 += 16) {
            __syncthreads();
            for (int k = tid; k < 16*3*OR; k += 256) {
                int ci = k / (3*OR); int rem = k - ci*(3*OR);
                int j = rem / OR; int oo = rem - j*OR;
                wst[k] = wbase[(cc0+ci)*384 + j*128 + obase + oo];
            }
            __syncthreads();
            for (int ci = 0; ci < 16; ++ci) {
                int c = cc0 + ci;
                float xv[3];
                #pragma unroll
                for (int j = 0; j < 3; ++j) {
                    int iu = p + j - 1;
                    xv[j] = ((unsigned)iu < (unsigned)L2) ? inb[c*Lin + (iu>>1)] : 0.f;
                }
                #pragma unroll
                for (int j = 0; j < 3; ++j) {
                    const float4* w4 = (const float4*)(wst + ci*3*OR + j*OR + o0);
                    #pragma unroll
                    for (int q = 0; q < NO/4; ++q) {
                        float4 w = w4[q];
                        acc[q*4+0] += xv[j]*w.x; acc[q*4+1] += xv[j]*w.y;
                        acc[q*4+2] += xv[j]*w.z; acc[q*4+3] += xv[j]*w.w;
                    }
                }
            }
        }
        #pragma unroll
        for (int k = 0; k < NO; ++k)
            outb[(obase + o0 + k)*L2 + p] = leakyf(acc[k] + bias[obase + o0 + k]);
    }
}

// ---------------- fused conv_up: gridDim=(128 events, 2 modes), 256 threads ----------------
// __launch_bounds__(256) is ESSENTIAL: without it hipcc budgets VGPRs for a possible
// 1024-thread block (r8: VGPR=64, 7.8GB scratch traffic). With it the true 256-thread
// size unlocks the full register budget (r2 precedent: 132 VGPR granted).
__global__ __launch_bounds__(256) void k_convup3(const float* __restrict__ lat,
    const float* __restrict__ elw, const float* __restrict__ elb, const float* __restrict__ ecb,
    const float* __restrict__ efw, const float* __restrict__ efb,
    const float* __restrict__ tlw, const float* __restrict__ tlb, const float* __restrict__ tcb,
    const float* __restrict__ tfb, const float* __restrict__ wtu, const float* __restrict__ wtf,
    float* __restrict__ envsq, float* __restrict__ tfT)
{
    __shared__ float pool[35008]; // 136.75 KB
    float* latv = pool;           // 128
    float* bufA = pool + 128;     // 4160: layers <=32-wide; later trb[32][129]=4128
    float* bufB = pool + 4288;    // 8192: 16- and 64-wide stages
    float* bufC = pool + 12480;   // 16384: [128][128]
    float* wst  = pool + 28864;   // 6144
    int ev = blockIdx.x;
    int m  = blockIdx.y;
    int tid = threadIdx.x;
    const float* lw = m ? tlw : elw;
    const float* lb = m ? tlb : elb;
    const float* cb = m ? tcb : ecb;
    const float* wu = wtu + m*4*49152;
    if (tid < 128) latv[tid] = lat[ev*128 + tid];
    __syncthreads();
    for (int jj = tid; jj < 1024; jj += 256) {
        float a = lb[jj];
        const float4* w4 = (const float4*)(lw + jj*128);
        #pragma unroll 8
        for (int q = 0; q < 32; ++q) {
            float4 w = w4[q];
            a += w.x*latv[q*4] + w.y*latv[q*4+1] + w.z*latv[q*4+2] + w.w*latv[q*4+3];
        }
        bufA[(jj>>3)*8 + (jj&7)] = a;
    }
    up_layerS<16,1>(wu,        cb,     bufA, bufB, wst, tid);   // [128][8] -> [128][16]
    up_layerS<32,1>(wu+49152,  cb+128, bufB, bufA, wst, tid);   // -> [128][32]
    up_layerS<64,2>(wu+98304,  cb+256, bufA, bufB, wst, tid);   // -> [128][64]
    up_layerS<128,4>(wu+147456,cb+384, bufB, bufC, wst, tid);   // -> [128][128]
    __syncthreads();
    int p = tid & 127, g = tid >> 7;  // g in 0..1
    if (m == 0) {
        float s = 0.f;
        for (int c = g*64; c < g*64+64; ++c) {
            #pragma unroll
            for (int j = 0; j < 3; ++j) {
                int iu = p + j - 1;
                float xv = ((unsigned)iu < 128u) ? bufC[c*128 + iu] : 0.f;
                s += efw[c*3+j]*xv;
            }
        }
        wst[g*128 + p] = s;
        __syncthreads();
        if (g == 0) {
            float a = wst[p] + wst[128+p] + efb[0];
            envsq[ev*128 + p] = a*a;
        }
    } else {
        float* trb = bufA;   // [32ct][stride 129]
        for (int ctb = 0; ctb < 17; ++ctb) {
            int ct0 = ctb*32;
            float acc[16];
            #pragma unroll
            for (int i = 0; i < 16; ++i) acc[i] = 0.f;
            for (int cc0 = 0; cc0 < 128; cc0 += 16) {
                __syncthreads();
                for (int k = tid; k < 1536; k += 256) {
                    int ci = k / 96, rem = k - ci*96;
                    int j = rem >> 5, ctl = rem & 31;
                    wst[k] = wtf[(cc0+ci)*1632 + j*544 + ct0 + ctl];
                }
                __syncthreads();
                for (int ci = 0; ci < 16; ++ci) {
                    int c = cc0 + ci;
                    float xv[3];
                    #pragma unroll
                    for (int j = 0; j < 3; ++j) {
                        int iu = p + j - 1;
                        xv[j] = ((unsigned)iu < 128u) ? bufC[c*128 + iu] : 0.f;
                    }
                    #pragma unroll
                    for (int j = 0; j < 3; ++j) {
                        const float4* w4 = (const float4*)(wst + ci*96 + j*32 + g*16);
                        #pragma unroll
                        for (int q = 0; q < 4; ++q) {
                            float4 w = w4[q];
                            acc[q*4+0] += xv[j]*w.x; acc[q*4+1] += xv[j]*w.y;
                            acc[q*4+2] += xv[j]*w.z; acc[q*4+3] += xv[j]*w.w;
                        }
                    }
                }
            }
            __syncthreads();      // prior trb readers done (stage/compute syncs above also fence)
            #pragma unroll
            for (int i = 0; i < 16; ++i) trb[(g*16 + i)*129 + p] = acc[i];
            __syncthreads();
            int ctl2 = tid & 31, pg = tid >> 5;   // 8 p-groups
            #pragma unroll
            for (int ps = 0; ps < 16; ++ps) {
                int pp = ps*8 + pg;
                int ct = ct0 + ctl2;
                if (ct < 514)
                    tfT[(size_t)(ev*128 + pp)*514 + ct] = trb[ctl2*129 + pp] + tfb[ct];
            }
            __syncthreads();
        }
    }
}

// ---------------- impulse transfer lin_stack ----------------
__global__ __launch_bounds__(128) void k_itf(const float* __restrict__ lat,
    const float* __restrict__ iw, const float* __restrict__ ib,
    const float* __restrict__ iow, const float* __restrict__ iob,
    float* __restrict__ itf)
{
    int ev = blockIdx.x; int tid = threadIdx.x;
    __shared__ float xa[128], xb[128];
    xa[tid] = lat[ev*128 + tid];
    __syncthreads();
    float* src = xa; float* dst = xb;
    for (int l = 0; l < 3; ++l) {
        float a = ib[l*128 + tid];
        const float* wr = iw + (l*128 + tid)*128;
        for (int k = 0; k < 128; ++k) a += wr[k]*src[k];
        dst[tid] = leakyf(a);
        __syncthreads();
        float* tmp = src; src = dst; dst = tmp;
    }
    for (int o = tid; o < 514; o += 128) {
        float a = iob[o];
        const float* wr = iow + o*128;
        for (int k = 0; k < 128; ++k) a += wr[k]*src[k];
        itf[ev*514 + o] = a;
    }
}

// ---------------- room/mix lin_stacks + softmax ----------------
__global__ __launch_bounds__(128) void k_roommix(const float* __restrict__ agg,
    const float* __restrict__ rw, const float* __restrict__ rb,
    const float* __restrict__ row_, const float* __restrict__ rob,
    const float* __restrict__ mw, const float* __restrict__ mb,
    const float* __restrict__ mow, const float* __restrict__ mob,
    float* __restrict__ probs, float* __restrict__ mval)
{
    int b = blockIdx.x; int tid = threadIdx.x;
    __shared__ float xa[128], xb[128], rr[8];
    xa[tid] = agg[b*128 + tid];
    __syncthreads();
    float* src = xa; float* dst = xb;
    for (int l = 0; l < 3; ++l) {
        float a = rb[l*128 + tid];
        const float* wr = rw + (l*128 + tid)*128;
        for (int k = 0; k < 128; ++k) a += wr[k]*src[k];
        dst[tid] = leakyf(a);
        __syncthreads();
        float* tmp = src; src = dst; dst = tmp;
    }
    if (tid < 8) {
        float a = rob[tid];
        const float* wr = row_ + tid*128;
        for (int k = 0; k < 128; ++k) a += wr[k]*src[k];
        rr[tid] = a;
    }
    __syncthreads();
    if (tid == 0) {
        float m = rr[0];
        for (int j = 1; j < 8; ++j) m = fmaxf(m, rr[j]);
        float ssum = 0.f; float e[8];
        for (int j = 0; j < 8; ++j) { e[j] = __expf(rr[j]-m); ssum += e[j]; }
        for (int j = 0; j < 8; ++j) probs[b*8+j] = e[j]/ssum;
    }
    __syncthreads();
    xa[tid] = agg[b*128 + tid];
    __syncthreads();
    src = xa; dst = xb;
    for (int l = 0; l < 3; ++l) {
        float a = mb[l*128 + tid];
        const float* wr = mw + (l*128 + tid)*128;
        for (int k = 0; k < 128; ++k) a += wr[k]*src[k];
        dst[tid] = leakyf(a);
        __syncthreads();
        float* tmp = src; src = dst; dst = tmp;
    }
    if (tid == 0) {
        float a = mob[0];
        for (int k = 0; k < 128; ++k) a += mow[k]*src[k];
        mval[b] = a;
    }
}

// ---------------- ir = softmax(r) @ rooms ----------------
__global__ void k_ir(const float* __restrict__ probs, const float* __restrict__ rooms, float* __restrict__ ir)
{
    int b = blockIdx.y;
    int t = blockIdx.x*256 + threadIdx.x;
    float a = 0.f;
    for (int j = 0; j < 8; ++j) a += probs[b*8+j]*rooms[j*NS + t];
    ir[b*NS + t] = a;
}

// ---------------- 512-pt complex FFT in LDS (256 threads) ----------------
__device__ __forceinline__ void fft512(float* re, float* im, const float* twr, const float* twi, int tid, bool inverse)
{
    for (int w = tid; w < 512; w += 256) {
        unsigned r = __brev((unsigned)w) >> 23;
        if ((int)r > w) {
            float tr = re[w]; re[w] = re[r]; re[r] = tr;
            float ti = im[w]; im[w] = im[r]; im[r] = ti;
        }
    }
    __syncthreads();
    for (int s = 0; s < 9; ++s) {
        int half = 1 << s;
        int grp = tid >> s;
        int pos = tid & (half-1);
        int i0 = (grp << (s+1)) + pos;
        int i1 = i0 + half;
        int twidx = pos << (8 - s);
        float wr = twr[twidx];
        float wi = inverse ? -twi[twidx] : twi[twidx];
        float r1 = re[i1], q1 = im[i1];
        float tr = wr*r1 - wi*q1;
        float ti = wr*q1 + wi*r1;
        float r0 = re[i0], q0 = im[i0];
        re[i1] = r0 - tr; im[i1] = q0 - ti;
        re[i0] = r0 + tr; im[i0] = q0 + ti;
        __syncthreads();
    }
}

// ---------------- per-event scan: impulse -> 128 frames of env*imp + carry -> FFT filter -> OLA ----------------
__global__ __launch_bounds__(256) void k_event(const float* __restrict__ tfT, const float* __restrict__ itf,
    const float* __restrict__ envsq, const float* __restrict__ noise, float* __restrict__ atoms)
{
    int ev = blockIdx.x; int tid = threadIdx.x;
    __shared__ float twr[256], twi[256];
    __shared__ float re[512], im[512], carry[512], imp[512], ham[512], acc[256], envl[128];
    if (tid < 128) envl[tid] = envsq[ev*128 + tid];
    {
        float ang = -6.283185307179586f * (float)tid / 512.0f;
        float si, co;
        sincosf(ang, &si, &co);
        twr[tid] = co; twi[tid] = si;
    }
    for (int w = tid; w < 512; w += 256) {
        ham[w] = 0.54f - 0.46f*cosf(6.283185307179586f * (float)w / 512.0f);
        re[w] = noise[w]; im[w] = 0.f; carry[w] = 0.f;
    }
    acc[tid] = 0.f;
    __syncthreads();
    fft512(re, im, twr, twi, tid, false);
    {
        const float* tp = itf + ev*514;
        int k = tid;
        float xr = re[k], xi = im[k];
        float tr = tp[2*k], ti = tp[2*k+1];
        float sr = xr*tr - xi*ti;
        float si = xr*ti + xi*tr;
        if (k == 0) si = 0.f;
        re[k] = sr; im[k] = si;
        if (k >= 1) { re[512-k] = sr; im[512-k] = -si; }
        if (tid == 0) {
            float xr2 = re[256], xi2 = im[256];
            float sr2 = xr2*tp[512] - xi2*tp[513];
            re[256] = sr2; im[256] = 0.f;
        }
    }
    __syncthreads();
    fft512(re, im, twr, twi, tid, true);
    for (int w = tid; w < 512; w += 256) imp[w] = re[w] * (1.0f/512.0f);
    __syncthreads();
    const float inv512 = 1.0f/512.0f;
    for (int f = 0; f < 128; ++f) {
        for (int w = tid; w < 512; w += 256) {
            int tg = f*256 + w;
            float e = 0.f;
            if (tg < NS) {
                float srcp = ((float)tg + 0.5f)*(1.0f/256.0f) - 0.5f;
                srcp = fminf(fmaxf(srcp, 0.f), 127.f);
                int i0 = (int)srcp;
                float fr = srcp - (float)i0;
                int i1 = i0 + 1; if (i1 > 127) i1 = 127;
                e = envl[i0]*(1.f-fr) + envl[i1]*fr;
            }
            re[w] = imp[w]*e + carry[w];
            im[w] = 0.f;
        }
        __syncthreads();
        fft512(re, im, twr, twi, tid, false);
        {
            const float* tp = tfT + ((size_t)ev*128 + f)*514;
            int k = tid;
            float xr = re[k], xi = im[k];
            float tr = tp[2*k], ti = tp[2*k+1];
            float sr = xr*tr - xi*ti;
            float si = xr*ti + xi*tr;
            if (k == 0) si = 0.f;
            re[k] = sr; im[k] = si;
            if (k >= 1) { re[512-k] = sr; im[512-k] = -si; }
            if (tid == 0) {
                float xr2 = re[256], xi2 = im[256];
                float sr2 = xr2*tp[512] - xi2*tp[513];
                re[256] = sr2; im[256] = 0.f;
            }
        }
        __syncthreads();
        fft512(re, im, twr, twi, tid, true);
        float o0 = re[tid]     * inv512 * ham[tid];
        float o1 = re[tid+256] * inv512 * ham[tid+256];
        atoms[(size_t)ev*NS + f*256 + tid] = o0 + acc[tid];
        acc[tid] = o1;
        carry[tid] = o0;
        carry[tid+256] = o1;
        __syncthreads();
    }
}

// ---------------- final = sum_a values[a]*atoms[a, t-idx[a]] ----------------
__global__ void k_gather(const float* __restrict__ atoms, const float* __restrict__ topv,
                         const int* __restrict__ topi, float* __restrict__ fin)
{
    int b = blockIdx.y;
    int t = blockIdx.x*256 + threadIdx.x;
    float s = 0.f;
    for (int a = 0; a < 32; ++a) {
        int ii = topi[b*32 + a];
        if (ii <= t) s += topv[b*32 + a] * atoms[(size_t)(b*32 + a)*NS + (t - ii)];
    }
    fin[b*NS + t] = s;
}

// ---------------- wet = final (*) ir (causal direct conv), out = m*wet + final*(1-m) ----------------
__global__ __launch_bounds__(256) void k_wet(const float* __restrict__ fin, const float* __restrict__ ir,
    const float* __restrict__ mval, float* __restrict__ out)
{
    int b = blockIdx.y;
    int t0 = blockIdx.x*256;
    int tid = threadIdx.x;
    __shared__ float fs[256];
    __shared__ float irw[512];
    float wet = 0.f;
    for (int c0 = 0; c0 <= t0; c0 += 256) {
        __syncthreads();
        fs[tid] = fin[b*NS + c0 + tid];
        int dmin = t0 - c0 - 255;
        for (int q = tid; q < 511; q += 256) {
            int dd = dmin + q;
            irw[q] = ((unsigned)dd < NS) ? ir[b*NS + dd] : 0.f;
        }
        __syncthreads();
        if (c0 < t0) {
            #pragma unroll 8
            for (int k = 0; k < 256; ++k) wet += fs[k]*irw[tid + 255 - k];
        } else {
            for (int k = 0; k <= tid; ++k) wet += fs[k]*irw[tid + 255 - k];
        }
    }
    float m = mval[b];
    float fv = fin[b*NS + t0 + tid];
    out[b*NS + t0 + tid] = m*wet + fv*(1.f - m);
}

extern "C" void kernel_launch(void* const* d_in, const int* in_sizes, int n_in,
                              void* d_out, int out_size, void* d_ws, size_t ws_size,
                              hipStream_t stream)
{
    (void)in_sizes; (void)n_in; (void)out_size; (void)ws_size;
    const float* x    = (const float*)d_in[0];
    const float* fbw  = (const float*)d_in[1];
    const float* dsw  = (const float*)d_in[2];
    const float* dsb  = (const float*)d_in[3];
    const float* dgw  = (const float*)d_in[4];
    const float* dgb  = (const float*)d_in[5];
    const float* dow  = (const float*)d_in[6];
    const float* dob  = (const float*)d_in[7];
    const float* dnw  = (const float*)d_in[8];
    const float* dnb  = (const float*)d_in[9];
    const float* elw  = (const float*)d_in[10];
    const float* elb  = (const float*)d_in[11];
    const float* ecw  = (const float*)d_in[12];
    const float* ecb  = (const float*)d_in[13];
    const float* efw  = (const float*)d_in[14];
    const float* efb  = (const float*)d_in[15];
    const float* tlw  = (const float*)d_in[16];
    const float* tlb  = (const float*)d_in[17];
    const float* tcw  = (const float*)d_in[18];
    const float* tcb  = (const float*)d_in[19];
    const float* tfw  = (const float*)d_in[20];
    const float* tfb  = (const float*)d_in[21];
    const float* iw   = (const float*)d_in[22];
    const float* ib   = (const float*)d_in[23];
    const float* iow  = (const float*)d_in[24];
    const float* iob  = (const float*)d_in[25];
    const float* rw   = (const float*)d_in[26];
    const float* rb   = (const float*)d_in[27];
    const float* row_ = (const float*)d_in[28];
    const float* rob  = (const float*)d_in[29];
    const float* mw   = (const float*)d_in[30];
    const float* mb   = (const float*)d_in[31];
    const float* mow  = (const float*)d_in[32];
    const float* mob  = (const float*)d_in[33];
    const float* rooms= (const float*)d_in[34];
    const float* noise= (const float*)d_in[35];

    float* ws   = (float*)d_ws;
    float* n0   = ws;                       // 16,777,216
    float* n1   = ws + 16777216;            // 16,777,216
    float* accb = ws + 33554432;            // 16,777,216
    float* wT   = ws + 50331648;            // 1,376,256
    float* woT  = ws + 51707904;            // 114,688
    float* wnT  = ws + 51822592;            // 114,688
    float* envsq= ws + 51937280;            // 16,384
    float* lat  = ws + 51953664;            // 16,384
    float* itfb = ws + 51970048;            // 65,792
    float* norms= ws + 52035840;            // 131,072
    float* topv = ws + 52166912;            // 128
    int*   topi = (int*)(ws + 52167040);    // 128
    float* agg  = ws + 52167168;            // 512
    float* probs= ws + 52167680;            // 32
    float* mval = ws + 52167712;            // 32
    float* irb  = ws + 52167744;            // 131,072
    float* fin  = ws + 52298816;            // 131,072
    float* tfT  = n0;                        // reuse after dilated stack is done
    float* atoms= n0 + 8421376;              // reuse (8.42M + 4.19M < 16.77M)
    float* wtu  = n1;                        // 393,216  (n1 free after stack)
    float* wtf  = n1 + 393216;               // 208,896

    float* out = (float*)d_out;

    k_wtrans<<<dim3((1376256+255)/256), dim3(256), 0, stream>>>(dsw, dgw, wT);
    k_wtrans2<<<dim3((114688+255)/256), dim3(256), 0, stream>>>(dow, dnw, woT, wnT);
    k_front<<<dim3(512,4), dim3(512), 0, stream>>>(x, fbw, n0);

    const int dil[7] = {1,3,9,27,81,243,1};
    float* cin = n0; float* cout = n1;
    for (int l = 0; l < 7; ++l) {
        k_layer<<<dim3(512,4), dim3(512), 0, stream>>>(
            cin, cout, accb, wT + l*98304,
            dsb + l*128, dgb + l*128,
            woT + l*16384, dob + l*128,
            wnT + l*16384, dnb + l*128,
            dil[l], l==0 ? 1 : 0);
        float* tmp = cin; cin = cout; cout = tmp;
    }
    k_norms<<<dim3(128,4), dim3(256), 0, stream>>>(accb, norms);
    k_topk<<<dim3(4), dim3(1024), 0, stream>>>(norms, topv, topi);
    k_latents<<<dim3(128), dim3(128), 0, stream>>>(accb, topi, lat);
    k_aggmax<<<dim3(512), dim3(256), 0, stream>>>(accb, agg);
    // n1 is dead after the stack (final n unused by the reference) -> carve conv_up weights from it
    k_wtrans_up<<<dim3(1536), dim3(256), 0, stream>>>(ecw, tcw, tfw, wtu, wtf);
    k_convup3<<<dim3(128,2), dim3(256), 0, stream>>>(lat, elw, elb, ecb, efw, efb,
                                                     tlw, tlb, tcb, tfb, wtu, wtf, envsq, tfT);
    k_itf<<<dim3(128), dim3(128), 0, stream>>>(lat, iw, ib, iow, iob, itfb);
    k_roommix<<<dim3(4), dim3(128), 0, stream>>>(agg, rw, rb, row_, rob, mw, mb, mow, mob, probs, mval);
    k_ir<<<dim3(128,4), dim3(256), 0, stream>>>(probs, rooms, irb);
    k_event<<<dim3(128), dim3(256), 0, stream>>>(tfT, itfb, envsq, noise, atoms);
    k_gather<<<dim3(128,4), dim3(256), 0, stream>>>(atoms, topv, topi, fin);
    k_wet<<<dim3(128,4), dim3(256), 0, stream>>>(fin, irb, mval, out);
}